// Round 5
// baseline (371.691 us; speedup 1.0000x reference)
//
#include <hip/hip_runtime.h>
#include <hip/hip_bf16.h>

// Transformer block: x += attn(LN1(x)); x += mlp(LN2(x))
// B=8, N=1024, C=512, H=8 heads, d=64, HID=2048, spatial 32x32.
// R2: dwconv tap-major. R3: fused attention. R4 lesson: depth-1 manual vmcnt
// pipeline + B-direct regressed (compiler waits defeat it); swizzle->0 conflicts
// verified. R5: R3 two-barrier GEMM + XOR swizzle (A and B) + split-K=4 for the
// grid-starved proj/fc2 (256 blocks -> 1024 = 4/CU TLP) with fp32 atomicAdd
// into prefilled bias+residual output.

typedef __attribute__((ext_vector_type(8))) short short8;   // 8 x bf16 (4 VGPRs)
typedef __attribute__((ext_vector_type(4))) short s16x4;    // 4 x bf16
typedef __attribute__((ext_vector_type(4))) float f32x4;    // MFMA accum

__device__ __forceinline__ float b2f(short s) {
    union { float f; unsigned u; } z; z.u = ((unsigned)(unsigned short)s) << 16; return z.f;
}
__device__ __forceinline__ short f2b(float f) {  // RNE
    union { float f; unsigned u; } z; z.f = f;
    unsigned r = (z.u + 0x7fffu + ((z.u >> 16) & 1u)) >> 16;
    return (short)r;
}

__device__ __forceinline__ void gload_lds16(const void* g, void* l) {
    // async global->LDS, 16B/lane; LDS dest = wave-uniform base + lane*16
    __builtin_amdgcn_global_load_lds(
        (const __attribute__((address_space(1))) void*)g,
        (__attribute__((address_space(3))) void*)l, 16, 0, 0);
}

// ---------------- weight fp32 -> bf16 convert (all 4 weight mats, one launch) ----
__global__ __launch_bounds__(256) void cvt_weights(
    const float* __restrict__ s0, const float* __restrict__ s1,
    const float* __restrict__ s2, const float* __restrict__ s3,
    short* __restrict__ d0, short* __restrict__ d1,
    short* __restrict__ d2, short* __restrict__ d3) {
    long i = (long)blockIdx.x * 256 + threadIdx.x;  // vec4 index, total 786432
    const float* s; short* d; long off;
    if (i < 196608)      { s = s0; d = d0; off = i; }
    else if (i < 262144) { s = s1; d = d1; off = i - 196608; }
    else if (i < 524288) { s = s2; d = d2; off = i - 262144; }
    else                 { s = s3; d = d3; off = i - 524288; }
    float4 v = ((const float4*)s)[off];
    ushort4 o;
    o.x = (unsigned short)f2b(v.x); o.y = (unsigned short)f2b(v.y);
    o.z = (unsigned short)f2b(v.z); o.w = (unsigned short)f2b(v.w);
    ((ushort4*)d)[off] = o;
}

// ---------------- dw_w [2048][9] -> tap-major [9][2048] fp32 -------------------
__global__ __launch_bounds__(256) void cvt_dw(
    const float* __restrict__ src, float* __restrict__ dst) {
    int i = blockIdx.x * 256 + threadIdx.x;   // 72 blocks -> 18432
    int t = i >> 11, c = i & 2047;
    dst[t * 2048 + c] = src[c * 9 + t];
}

// ---------------- prefill: dst[r][o] = src[r][o] + bias[o]  (fp32, 8192x512) ---
__global__ __launch_bounds__(256) void prefill_bias_res(
    const float* __restrict__ src, const float* __restrict__ bias,
    float* __restrict__ dst) {
    long i = (long)blockIdx.x * 256 + threadIdx.x;  // float4 idx, total 1048576
    int o4 = (int)(i & 127);
    float4 s = ((const float4*)src)[i];
    float4 bv = ((const float4*)bias)[o4];
    float4 d = {s.x + bv.x, s.y + bv.y, s.z + bv.z, s.w + bv.w};
    ((float4*)dst)[i] = d;
}

// ---------------- layernorm: fp32 [8192][512] -> bf16, one wave per row --------
__global__ __launch_bounds__(256) void ln_kernel(
    const float* __restrict__ x, const float* __restrict__ g,
    const float* __restrict__ b, short* __restrict__ y) {
    int row  = blockIdx.x * 4 + (threadIdx.x >> 6);
    int lane = threadIdx.x & 63;
    const float* xr = x + (long)row * 512 + lane * 8;
    float4 v0 = ((const float4*)xr)[0];
    float4 v1 = ((const float4*)xr)[1];
    float e0[8] = {v0.x, v0.y, v0.z, v0.w, v1.x, v1.y, v1.z, v1.w};
    float s = 0.f;
#pragma unroll
    for (int e = 0; e < 8; e++) s += e0[e];
#pragma unroll
    for (int d = 1; d < 64; d <<= 1) s += __shfl_xor(s, d);
    float mu = s * (1.0f / 512.0f);
    float q = 0.f;
#pragma unroll
    for (int e = 0; e < 8; e++) { float t = e0[e] - mu; q += t * t; }
#pragma unroll
    for (int d = 1; d < 64; d <<= 1) q += __shfl_xor(q, d);
    float rs = rsqrtf(q * (1.0f / 512.0f) + 1e-5f);
    const float* gp = g + lane * 8;
    const float* bp = b + lane * 8;
    short8 o;
#pragma unroll
    for (int e = 0; e < 8; e++) o[e] = f2b((e0[e] - mu) * rs * gp[e] + bp[e]);
    *(short8*)(y + (long)row * 512 + lane * 8) = o;
}

// ---------------- GEMM: C[r][o] = sum_c A[r][c]*B[o][c], A,B bf16 --------------
// 128x128 tile, BK=32, 4 waves each 64x64 (4x4 MFMA frags). R3 two-barrier
// structure + XOR chunk swizzle on As/Bs (LDS slot s holds global chunk
// s ^ ((row>>1)&3)) -> 0 bank conflicts (verified R4). Optional split-K via
// blockIdx.z * kloc (epilogue must then accumulate atomically).
template <typename Epi>
__global__ __launch_bounds__(256, 4) void gemm_bt(
    const short* __restrict__ A, const short* __restrict__ B, int K, int kloc,
    Epi epi) {
    __shared__ short As[128 * 32];
    __shared__ short Bs[128 * 32];
    int tid = threadIdx.x;
    int lane = tid & 63, w = tid >> 6;
    int lr = lane & 15, lq = lane >> 4;
    int wm = (w & 1) * 64, wn = (w >> 1) * 64;
    long r0 = (long)blockIdx.x * 128, o0 = (long)blockIdx.y * 128;
    int kbase = blockIdx.z * kloc;
    f32x4 acc[4][4];
#pragma unroll
    for (int i = 0; i < 4; i++)
#pragma unroll
        for (int j = 0; j < 4; j++) acc[i][j] = (f32x4){0.f, 0.f, 0.f, 0.f};
    const short* Ab = A + r0 * K;
    const short* Bb = B + o0 * K;
    int srow = tid >> 2;          // 0..63 (staging row; +64 for second set)
    int sc = ((tid & 3) ^ ((srow >> 1) & 3)) * 8;   // XOR-swizzled source chunk
    for (int k0 = kbase; k0 < kbase + kloc; k0 += 32) {
        gload_lds16(Ab + (long)srow * K + k0 + sc,        As + w * 512);
        gload_lds16(Ab + (long)(srow + 64) * K + k0 + sc, As + (w + 4) * 512);
        gload_lds16(Bb + (long)srow * K + k0 + sc,        Bs + w * 512);
        gload_lds16(Bb + (long)(srow + 64) * K + k0 + sc, Bs + (w + 4) * 512);
        __syncthreads();
        short8 af[4], bfr[4];
#pragma unroll
        for (int i = 0; i < 4; i++) {
            int row = wm + i * 16 + lr;
            af[i] = *(const short8*)&As[row * 32 + ((lq ^ ((row >> 1) & 3)) * 8)];
        }
#pragma unroll
        for (int j = 0; j < 4; j++) {
            int row = wn + j * 16 + lr;
            bfr[j] = *(const short8*)&Bs[row * 32 + ((lq ^ ((row >> 1) & 3)) * 8)];
        }
#pragma unroll
        for (int i = 0; i < 4; i++)
#pragma unroll
            for (int j = 0; j < 4; j++)
                acc[i][j] = __builtin_amdgcn_mfma_f32_16x16x32_bf16(
                    af[i], bfr[j], acc[i][j], 0, 0, 0);
        __syncthreads();
    }
    // C/D layout: col = lane&15, row = (lane>>4)*4 + reg  [m89/m91 verified]
#pragma unroll
    for (int i = 0; i < 4; i++)
#pragma unroll
        for (int j = 0; j < 4; j++)
#pragma unroll
            for (int rg = 0; rg < 4; rg++)
                epi((int)(r0 + wm + i * 16 + lq * 4 + rg),
                    (int)(o0 + wn + j * 16 + lr), acc[i][j][rg]);
}

// epilogues
struct EpiQKV {   // scatter qkv -> q[bh][n][d], k[bh][n][d], vt[bh][d][n]
    short *q, *k, *vt;
    __device__ void operator()(int r, int o, float v) const {
        int b = r >> 10, n = r & 1023;
        int h = o / 192, j = o - h * 192;
        int bh = b * 8 + h;
        short bv = f2b(v);
        if (j < 64)        q[((long)bh * 1024 + n) * 64 + j] = bv;
        else if (j < 128)  k[((long)bh * 1024 + n) * 64 + (j - 64)] = bv;
        else               vt[((long)bh * 64 + (j - 128)) * 1024 + n] = bv;
    }
};
struct EpiBias {  // h1 = bf16(acc + bias)
    const float* bias; short* out; int O;
    __device__ void operator()(int r, int o, float v) const {
        out[(long)r * O + o] = f2b(v + bias[o]);
    }
};
struct EpiAtomic {  // dst[r][o] += v  (fp32, prefilled with bias+residual)
    float* dst;
    __device__ void operator()(int r, int o, float v) const {
        atomicAdd(dst + (long)r * 512 + o, v);
    }
};

// ---------------- fused attention (R3 structure, unchanged) --------------------
__global__ __launch_bounds__(256, 2) void attn_kernel(
    const short* __restrict__ Q, const short* __restrict__ K,
    const short* __restrict__ Vt, short* __restrict__ out) {
    __shared__ __align__(16) char smem[53248];
    int bh = blockIdx.x, qb = blockIdx.y;
    int tid = threadIdx.x, w = tid >> 6, lane = tid & 63;
    int lr = lane & 15, lq = lane >> 4;
    short* Kt = (short*)(smem + w * 13312);
    short* Vl = (short*)(smem + w * 13312 + 4096);
    short* Pt = (short*)(smem + w * 13312 + 8192);
    short* Oshb = (short*)smem;                    // 36864 B
    float* Lsh  = (float*)(smem + 36864);          // 1024 B

    const short* Qb = Q + ((long)bh * 1024 + qb * 64) * 64;
    const short* Kb = K + (long)bh * 1024 * 64;
    const short* Vb = Vt + (long)bh * 64 * 1024;

    short8 qf[4][2];
#pragma unroll
    for (int jt = 0; jt < 4; jt++)
#pragma unroll
        for (int ks = 0; ks < 2; ks++)
            qf[jt][ks] = *(const short8*)(Qb + (jt * 16 + lr) * 64 + ks * 32 + lq * 8);

    f32x4 oacc[4][4];
#pragma unroll
    for (int mt = 0; mt < 4; mt++)
#pragma unroll
        for (int dt = 0; dt < 4; dt++) oacc[mt][dt] = (f32x4){0.f, 0.f, 0.f, 0.f};
    float lsum[4] = {0.f, 0.f, 0.f, 0.f};

    for (int it = 0; it < 8; it++) {
        int n0 = w * 256 + it * 32;
#pragma unroll
        for (int i = 0; i < 4; i++) {
            int s = i * 64 + lane;
            int row = s >> 3, ch = (s & 7) ^ (row & 7);
            gload_lds16(Kb + (long)(n0 + row) * 64 + ch * 8, Kt + i * 512);
        }
#pragma unroll
        for (int i = 0; i < 4; i++) {
            int s = i * 64 + lane;
            int row = s >> 2, ch = s & 3;
            gload_lds16(Vb + (long)row * 1024 + n0 + ch * 8, Vl + i * 512);
        }
        asm volatile("s_waitcnt vmcnt(0)" ::: "memory");
        f32x4 sacc[2][4];
#pragma unroll
        for (int kt = 0; kt < 2; kt++)
#pragma unroll
            for (int jt = 0; jt < 4; jt++) sacc[kt][jt] = (f32x4){0.f, 0.f, 0.f, 0.f};
#pragma unroll
        for (int ks = 0; ks < 2; ks++)
#pragma unroll
            for (int kt = 0; kt < 2; kt++) {
                short8 ak = *(const short8*)&Kt[(kt * 16 + lr) * 64 +
                                                (((ks * 4 + lq) ^ (lr & 7)) * 8)];
#pragma unroll
                for (int jt = 0; jt < 4; jt++)
                    sacc[kt][jt] = __builtin_amdgcn_mfma_f32_16x16x32_bf16(
                        ak, qf[jt][ks], sacc[kt][jt], 0, 0, 0);
            }
#pragma unroll
        for (int kt = 0; kt < 2; kt++)
#pragma unroll
            for (int jt = 0; jt < 4; jt++) {
                s16x4 pv;
#pragma unroll
                for (int rg = 0; rg < 4; rg++) {
                    float e = __expf(sacc[kt][jt][rg] * 0.125f);
                    lsum[jt] += e;
                    pv[rg] = f2b(e);
                }
                *(s16x4*)&Pt[(jt * 16 + lr) * 40 + kt * 16 + lq * 4] = pv;
            }
        short8 bv[4];
#pragma unroll
        for (int dt = 0; dt < 4; dt++)
            bv[dt] = *(const short8*)&Vl[(dt * 16 + lr) * 32 + lq * 8];
#pragma unroll
        for (int mt = 0; mt < 4; mt++) {
            short8 ap = *(const short8*)&Pt[(mt * 16 + lr) * 40 + lq * 8];
#pragma unroll
            for (int dt = 0; dt < 4; dt++)
                oacc[mt][dt] = __builtin_amdgcn_mfma_f32_16x16x32_bf16(
                    ap, bv[dt], oacc[mt][dt], 0, 0, 0);
        }
    }
#pragma unroll
    for (int jt = 0; jt < 4; jt++) {
        lsum[jt] += __shfl_xor(lsum[jt], 16);
        lsum[jt] += __shfl_xor(lsum[jt], 32);
    }
    __syncthreads();
#pragma unroll
    for (int mt = 0; mt < 4; mt++)
#pragma unroll
        for (int dt = 0; dt < 4; dt++)
#pragma unroll
            for (int rg = 0; rg < 4; rg++)
                Oshb[w * 4608 + (mt * 16 + lq * 4 + rg) * 72 + dt * 16 + lr] =
                    f2b(oacc[mt][dt][rg]);
    if (lq == 0)
#pragma unroll
        for (int jt = 0; jt < 4; jt++) Lsh[w * 64 + jt * 16 + lr] = lsum[jt];
    __syncthreads();
    int m = tid >> 2, dg = (tid & 3) * 16;
    float l = Lsh[m] + Lsh[64 + m] + Lsh[128 + m] + Lsh[192 + m];
    float inv = 1.0f / l;
    float r[16];
#pragma unroll
    for (int i = 0; i < 16; i++) r[i] = 0.f;
#pragma unroll
    for (int ww = 0; ww < 4; ww++) {
        const short8* op = (const short8*)&Oshb[ww * 4608 + m * 72 + dg];
        short8 a = op[0], bq = op[1];
#pragma unroll
        for (int i = 0; i < 8; i++) { r[i] += b2f(a[i]); r[8 + i] += b2f(bq[i]); }
    }
    short8 o0, o1;
#pragma unroll
    for (int i = 0; i < 8; i++) { o0[i] = f2b(r[i] * inv); o1[i] = f2b(r[8 + i] * inv); }
    int b = bh >> 3, h = bh & 7;
    long base = ((long)(b * 1024 + qb * 64 + m)) * 512 + h * 64 + dg;
    *(short8*)(out + base) = o0;
    *(short8*)(out + base + 8) = o1;
}

// ---------------- depthwise 3x3 conv + bias + exact GeLU -----------------------
__global__ __launch_bounds__(256) void dwconv_gelu(
    const short* __restrict__ h1, const float* __restrict__ wdT,
    const float* __restrict__ bias, short* __restrict__ h2) {
    int bn = blockIdx.x;                  // (b, n)
    int b = bn >> 10, n = bn & 1023;
    int yy = n >> 5, xx = n & 31;
    int c0 = threadIdx.x * 8;
    float4 bv0 = ((const float4*)&bias[c0])[0];
    float4 bv1 = ((const float4*)&bias[c0])[1];
    float acc[8] = {bv0.x, bv0.y, bv0.z, bv0.w, bv1.x, bv1.y, bv1.z, bv1.w};
    for (int ky = 0; ky < 3; ky++) {
        int ys = yy + ky - 1;
        if (ys < 0 || ys > 31) continue;
        for (int kx = 0; kx < 3; kx++) {
            int xs = xx + kx - 1;
            if (xs < 0 || xs > 31) continue;
            short8 hv = *(const short8*)&h1[((long)(b * 1024 + ys * 32 + xs)) * 2048 + c0];
            const float4* wp = (const float4*)&wdT[(ky * 3 + kx) * 2048 + c0];
            float4 wa = wp[0], wb = wp[1];
            float wv[8] = {wa.x, wa.y, wa.z, wa.w, wb.x, wb.y, wb.z, wb.w};
#pragma unroll
            for (int e = 0; e < 8; e++)
                acc[e] += b2f(hv[e]) * wv[e];
        }
    }
    short8 o;
#pragma unroll
    for (int e = 0; e < 8; e++) {
        float a = acc[e];
        o[e] = f2b(0.5f * a * (1.0f + erff(a * 0.70710678118f)));
    }
    *(short8*)&h2[((long)bn) * 2048 + c0] = o;
}

// ---------------- driver --------------------------------------------------------
extern "C" void kernel_launch(void* const* d_in, const int* in_sizes, int n_in,
                              void* d_out, int out_size, void* d_ws, size_t ws_size,
                              hipStream_t stream) {
    const float* x      = (const float*)d_in[0];
    const float* ln1_g  = (const float*)d_in[1];
    const float* ln1_b  = (const float*)d_in[2];
    const float* qkv_w  = (const float*)d_in[3];
    const float* proj_w = (const float*)d_in[4];
    const float* proj_b = (const float*)d_in[5];
    const float* ln2_g  = (const float*)d_in[6];
    const float* ln2_b  = (const float*)d_in[7];
    const float* fc1_w  = (const float*)d_in[8];
    const float* fc1_b  = (const float*)d_in[9];
    const float* dw_w   = (const float*)d_in[10];
    const float* dw_b   = (const float*)d_in[11];
    const float* fc2_w  = (const float*)d_in[12];
    const float* fc2_b  = (const float*)d_in[13];
    float* out = (float*)d_out;

    char* p = (char*)d_ws;
    short* wq   = (short*)p; p += (long)1536 * 512 * 2;
    short* wp   = (short*)p; p += (long)512 * 512 * 2;
    short* w1   = (short*)p; p += (long)2048 * 512 * 2;
    short* w2   = (short*)p; p += (long)512 * 2048 * 2;
    float* wdT  = (float*)p; p += (long)9 * 2048 * 4;
    short* y1   = (short*)p; p += (long)8192 * 512 * 2;
    short* q    = (short*)p; p += (long)64 * 1024 * 64 * 2;
    short* k    = (short*)p; p += (long)64 * 1024 * 64 * 2;
    short* vt   = (short*)p; p += (long)64 * 64 * 1024 * 2;
    short* attn = (short*)p; p += (long)8192 * 512 * 2;
    float* x1   = (float*)p; p += (long)8192 * 512 * 4;
    short* y2   = (short*)p; p += (long)8192 * 512 * 2;
    short* h1   = (short*)p; p += (long)8192 * 2048 * 2;
    short* h2   = (short*)p; p += (long)8192 * 2048 * 2;
    if ((size_t)(p - (char*)d_ws) > ws_size) return;  // ws too small: fail loudly

    cvt_weights<<<3072, 256, 0, stream>>>(qkv_w, proj_w, fc1_w, fc2_w, wq, wp, w1, w2);
    cvt_dw<<<72, 256, 0, stream>>>(dw_w, wdT);
    ln_kernel<<<2048, 256, 0, stream>>>(x, ln1_g, ln1_b, y1);
    gemm_bt<EpiQKV><<<dim3(64, 12, 1), 256, 0, stream>>>(y1, wq, 512, 512,
                                                         EpiQKV{q, k, vt});
    attn_kernel<<<dim3(64, 16), 256, 0, stream>>>(q, k, vt, attn);
    // proj (split-K=4): x1 = x + proj_b (+= attn @ proj_w^T via atomics)
    prefill_bias_res<<<4096, 256, 0, stream>>>(x, proj_b, x1);
    gemm_bt<EpiAtomic><<<dim3(64, 4, 4), 256, 0, stream>>>(attn, wp, 512, 128,
                                                           EpiAtomic{x1});
    ln_kernel<<<2048, 256, 0, stream>>>(x1, ln2_g, ln2_b, y2);
    gemm_bt<EpiBias><<<dim3(64, 16, 1), 256, 0, stream>>>(y2, w1, 512, 512,
                                                          EpiBias{fc1_b, h1, 2048});
    dwconv_gelu<<<8192, 256, 0, stream>>>(h1, wdT, dw_b, h2);
    // fc2 (split-K=4): out = x1 + fc2_b (+= h2 @ fc2_w^T via atomics)
    prefill_bias_res<<<4096, 256, 0, stream>>>(x1, fc2_b, out);
    gemm_bt<EpiAtomic><<<dim3(64, 4, 4), 256, 0, stream>>>(h2, w2, 2048, 512,
                                                           EpiAtomic{out});
}

// Round 6
// 297.023 us; speedup vs baseline: 1.2514x; 1.2514x over previous
//
#include <hip/hip_runtime.h>
#include <hip/hip_bf16.h>

// Transformer block: x += attn(LN1(x)); x += mlp(LN2(x))
// B=8, N=1024, C=512, H=8 heads, d=64, HID=2048, spatial 32x32.
// R2: dwconv tap-major. R3: fused attention. R4: XOR swizzle -> 0 LDS conflicts
// (verified; pipeline part reverted). R5 lesson: split-K atomics = 4x write
// amplification, net loss. R6: R3 two-barrier GEMM + swizzle; proj/fc2 use
// 64x128 tiles (grid 128x4 = 512 blocks = 2/CU TLP, full-K, single write,
// A refetch x4 absorbed by L3).

typedef __attribute__((ext_vector_type(8))) short short8;   // 8 x bf16 (4 VGPRs)
typedef __attribute__((ext_vector_type(4))) short s16x4;    // 4 x bf16
typedef __attribute__((ext_vector_type(4))) float f32x4;    // MFMA accum

__device__ __forceinline__ float b2f(short s) {
    union { float f; unsigned u; } z; z.u = ((unsigned)(unsigned short)s) << 16; return z.f;
}
__device__ __forceinline__ short f2b(float f) {  // RNE
    union { float f; unsigned u; } z; z.f = f;
    unsigned r = (z.u + 0x7fffu + ((z.u >> 16) & 1u)) >> 16;
    return (short)r;
}

__device__ __forceinline__ void gload_lds16(const void* g, void* l) {
    // async global->LDS, 16B/lane; LDS dest = wave-uniform base + lane*16
    __builtin_amdgcn_global_load_lds(
        (const __attribute__((address_space(1))) void*)g,
        (__attribute__((address_space(3))) void*)l, 16, 0, 0);
}

// ---------------- weight fp32 -> bf16 convert (all 4 weight mats, one launch) ----
__global__ __launch_bounds__(256) void cvt_weights(
    const float* __restrict__ s0, const float* __restrict__ s1,
    const float* __restrict__ s2, const float* __restrict__ s3,
    short* __restrict__ d0, short* __restrict__ d1,
    short* __restrict__ d2, short* __restrict__ d3) {
    long i = (long)blockIdx.x * 256 + threadIdx.x;  // vec4 index, total 786432
    const float* s; short* d; long off;
    if (i < 196608)      { s = s0; d = d0; off = i; }
    else if (i < 262144) { s = s1; d = d1; off = i - 196608; }
    else if (i < 524288) { s = s2; d = d2; off = i - 262144; }
    else                 { s = s3; d = d3; off = i - 524288; }
    float4 v = ((const float4*)s)[off];
    ushort4 o;
    o.x = (unsigned short)f2b(v.x); o.y = (unsigned short)f2b(v.y);
    o.z = (unsigned short)f2b(v.z); o.w = (unsigned short)f2b(v.w);
    ((ushort4*)d)[off] = o;
}

// ---------------- dw_w [2048][9] -> tap-major [9][2048] fp32 -------------------
__global__ __launch_bounds__(256) void cvt_dw(
    const float* __restrict__ src, float* __restrict__ dst) {
    int i = blockIdx.x * 256 + threadIdx.x;   // 72 blocks -> 18432
    int t = i >> 11, c = i & 2047;
    dst[t * 2048 + c] = src[c * 9 + t];
}

// ---------------- layernorm: fp32 [8192][512] -> bf16, one wave per row --------
__global__ __launch_bounds__(256) void ln_kernel(
    const float* __restrict__ x, const float* __restrict__ g,
    const float* __restrict__ b, short* __restrict__ y) {
    int row  = blockIdx.x * 4 + (threadIdx.x >> 6);
    int lane = threadIdx.x & 63;
    const float* xr = x + (long)row * 512 + lane * 8;
    float4 v0 = ((const float4*)xr)[0];
    float4 v1 = ((const float4*)xr)[1];
    float e0[8] = {v0.x, v0.y, v0.z, v0.w, v1.x, v1.y, v1.z, v1.w};
    float s = 0.f;
#pragma unroll
    for (int e = 0; e < 8; e++) s += e0[e];
#pragma unroll
    for (int d = 1; d < 64; d <<= 1) s += __shfl_xor(s, d);
    float mu = s * (1.0f / 512.0f);
    float q = 0.f;
#pragma unroll
    for (int e = 0; e < 8; e++) { float t = e0[e] - mu; q += t * t; }
#pragma unroll
    for (int d = 1; d < 64; d <<= 1) q += __shfl_xor(q, d);
    float rs = rsqrtf(q * (1.0f / 512.0f) + 1e-5f);
    const float* gp = g + lane * 8;
    const float* bp = b + lane * 8;
    short8 o;
#pragma unroll
    for (int e = 0; e < 8; e++) o[e] = f2b((e0[e] - mu) * rs * gp[e] + bp[e]);
    *(short8*)(y + (long)row * 512 + lane * 8) = o;
}

// ---------------- GEMM: C[r][o] = sum_c A[r][c]*B[o][c], A,B bf16 --------------
// MT x 128 tile, BK=32, 4 waves. MT=128: waves 2x2, 4x4 frags (m97 structure).
// MT=64: waves 1x4 (each 64x32), 4x2 frags -> grid gets 2x blocks for
// TLP-starved shapes. XOR chunk swizzle on As/Bs (slot s holds global chunk
// s ^ ((row>>1)&3)) -> 0 bank conflicts (verified R4/R5).
template <int MT, typename Epi>
__global__ __launch_bounds__(256, 4) void gemm_bt(
    const short* __restrict__ A, const short* __restrict__ B, int K, Epi epi) {
    constexpr int NJ = (MT == 128) ? 4 : 2;   // n-frags per wave
    __shared__ short As[MT * 32];
    __shared__ short Bs[128 * 32];
    int tid = threadIdx.x;
    int lane = tid & 63, w = tid >> 6;
    int lr = lane & 15, lq = lane >> 4;
    int wm = (MT == 128) ? (w & 1) * 64 : 0;
    int wn = (MT == 128) ? (w >> 1) * 64 : w * 32;
    long r0 = (long)blockIdx.x * MT, o0 = (long)blockIdx.y * 128;
    f32x4 acc[4][NJ];
#pragma unroll
    for (int i = 0; i < 4; i++)
#pragma unroll
        for (int j = 0; j < NJ; j++) acc[i][j] = (f32x4){0.f, 0.f, 0.f, 0.f};
    const short* Ab = A + r0 * K;
    const short* Bb = B + o0 * K;
    int srow = tid >> 2;          // 0..63 staging row (+64 second set)
    int sc = ((tid & 3) ^ ((srow >> 1) & 3)) * 8;   // XOR-swizzled source chunk
    for (int k0 = 0; k0 < K; k0 += 32) {
        gload_lds16(Ab + (long)srow * K + k0 + sc, As + w * 512);
        if (MT == 128)
            gload_lds16(Ab + (long)(srow + 64) * K + k0 + sc, As + (w + 4) * 512);
        gload_lds16(Bb + (long)srow * K + k0 + sc,        Bs + w * 512);
        gload_lds16(Bb + (long)(srow + 64) * K + k0 + sc, Bs + (w + 4) * 512);
        __syncthreads();
        short8 af[4], bfr[NJ];
#pragma unroll
        for (int i = 0; i < 4; i++) {
            int row = wm + i * 16 + lr;
            af[i] = *(const short8*)&As[row * 32 + ((lq ^ ((row >> 1) & 3)) * 8)];
        }
#pragma unroll
        for (int j = 0; j < NJ; j++) {
            int row = wn + j * 16 + lr;
            bfr[j] = *(const short8*)&Bs[row * 32 + ((lq ^ ((row >> 1) & 3)) * 8)];
        }
#pragma unroll
        for (int i = 0; i < 4; i++)
#pragma unroll
            for (int j = 0; j < NJ; j++)
                acc[i][j] = __builtin_amdgcn_mfma_f32_16x16x32_bf16(
                    af[i], bfr[j], acc[i][j], 0, 0, 0);
        __syncthreads();
    }
    // C/D layout: col = lane&15, row = (lane>>4)*4 + reg  [m89/m91 verified]
#pragma unroll
    for (int i = 0; i < 4; i++)
#pragma unroll
        for (int j = 0; j < NJ; j++)
#pragma unroll
            for (int rg = 0; rg < 4; rg++)
                epi((int)(r0 + wm + i * 16 + lq * 4 + rg),
                    (int)(o0 + wn + j * 16 + lr), acc[i][j][rg]);
}

// epilogues
struct EpiQKV {   // scatter qkv -> q[bh][n][d], k[bh][n][d], vt[bh][d][n]
    short *q, *k, *vt;
    __device__ void operator()(int r, int o, float v) const {
        int b = r >> 10, n = r & 1023;
        int h = o / 192, j = o - h * 192;
        int bh = b * 8 + h;
        short bv = f2b(v);
        if (j < 64)        q[((long)bh * 1024 + n) * 64 + j] = bv;
        else if (j < 128)  k[((long)bh * 1024 + n) * 64 + (j - 64)] = bv;
        else               vt[((long)bh * 64 + (j - 128)) * 1024 + n] = bv;
    }
};
struct EpiProj {  // x1 = acc + proj_b + x   (fp32)
    const float* pb; const float* x; float* x1;
    __device__ void operator()(int r, int o, float v) const {
        long idx = (long)r * 512 + o;
        x1[idx] = v + pb[o] + x[idx];
    }
};
struct EpiBias {  // h1 = bf16(acc + bias)
    const float* bias; short* out; int O;
    __device__ void operator()(int r, int o, float v) const {
        out[(long)r * O + o] = f2b(v + bias[o]);
    }
};
struct EpiFc2 {   // out = acc + fc2_b + x1  (fp32)
    const float* bias; const float* x1; float* out;
    __device__ void operator()(int r, int o, float v) const {
        long idx = (long)r * 512 + o;
        out[idx] = v + bias[o] + x1[idx];
    }
};

// ---------------- fused attention (R3 structure, unchanged) --------------------
__global__ __launch_bounds__(256, 2) void attn_kernel(
    const short* __restrict__ Q, const short* __restrict__ K,
    const short* __restrict__ Vt, short* __restrict__ out) {
    __shared__ __align__(16) char smem[53248];
    int bh = blockIdx.x, qb = blockIdx.y;
    int tid = threadIdx.x, w = tid >> 6, lane = tid & 63;
    int lr = lane & 15, lq = lane >> 4;
    short* Kt = (short*)(smem + w * 13312);
    short* Vl = (short*)(smem + w * 13312 + 4096);
    short* Pt = (short*)(smem + w * 13312 + 8192);
    short* Oshb = (short*)smem;                    // 36864 B
    float* Lsh  = (float*)(smem + 36864);          // 1024 B

    const short* Qb = Q + ((long)bh * 1024 + qb * 64) * 64;
    const short* Kb = K + (long)bh * 1024 * 64;
    const short* Vb = Vt + (long)bh * 64 * 1024;

    short8 qf[4][2];
#pragma unroll
    for (int jt = 0; jt < 4; jt++)
#pragma unroll
        for (int ks = 0; ks < 2; ks++)
            qf[jt][ks] = *(const short8*)(Qb + (jt * 16 + lr) * 64 + ks * 32 + lq * 8);

    f32x4 oacc[4][4];
#pragma unroll
    for (int mt = 0; mt < 4; mt++)
#pragma unroll
        for (int dt = 0; dt < 4; dt++) oacc[mt][dt] = (f32x4){0.f, 0.f, 0.f, 0.f};
    float lsum[4] = {0.f, 0.f, 0.f, 0.f};

    for (int it = 0; it < 8; it++) {
        int n0 = w * 256 + it * 32;
#pragma unroll
        for (int i = 0; i < 4; i++) {
            int s = i * 64 + lane;
            int row = s >> 3, ch = (s & 7) ^ (row & 7);
            gload_lds16(Kb + (long)(n0 + row) * 64 + ch * 8, Kt + i * 512);
        }
#pragma unroll
        for (int i = 0; i < 4; i++) {
            int s = i * 64 + lane;
            int row = s >> 2, ch = s & 3;
            gload_lds16(Vb + (long)row * 1024 + n0 + ch * 8, Vl + i * 512);
        }
        asm volatile("s_waitcnt vmcnt(0)" ::: "memory");
        f32x4 sacc[2][4];
#pragma unroll
        for (int kt = 0; kt < 2; kt++)
#pragma unroll
            for (int jt = 0; jt < 4; jt++) sacc[kt][jt] = (f32x4){0.f, 0.f, 0.f, 0.f};
#pragma unroll
        for (int ks = 0; ks < 2; ks++)
#pragma unroll
            for (int kt = 0; kt < 2; kt++) {
                short8 ak = *(const short8*)&Kt[(kt * 16 + lr) * 64 +
                                                (((ks * 4 + lq) ^ (lr & 7)) * 8)];
#pragma unroll
                for (int jt = 0; jt < 4; jt++)
                    sacc[kt][jt] = __builtin_amdgcn_mfma_f32_16x16x32_bf16(
                        ak, qf[jt][ks], sacc[kt][jt], 0, 0, 0);
            }
#pragma unroll
        for (int kt = 0; kt < 2; kt++)
#pragma unroll
            for (int jt = 0; jt < 4; jt++) {
                s16x4 pv;
#pragma unroll
                for (int rg = 0; rg < 4; rg++) {
                    float e = __expf(sacc[kt][jt][rg] * 0.125f);
                    lsum[jt] += e;
                    pv[rg] = f2b(e);
                }
                *(s16x4*)&Pt[(jt * 16 + lr) * 40 + kt * 16 + lq * 4] = pv;
            }
        short8 bv[4];
#pragma unroll
        for (int dt = 0; dt < 4; dt++)
            bv[dt] = *(const short8*)&Vl[(dt * 16 + lr) * 32 + lq * 8];
#pragma unroll
        for (int mt = 0; mt < 4; mt++) {
            short8 ap = *(const short8*)&Pt[(mt * 16 + lr) * 40 + lq * 8];
#pragma unroll
            for (int dt = 0; dt < 4; dt++)
                oacc[mt][dt] = __builtin_amdgcn_mfma_f32_16x16x32_bf16(
                    ap, bv[dt], oacc[mt][dt], 0, 0, 0);
        }
    }
#pragma unroll
    for (int jt = 0; jt < 4; jt++) {
        lsum[jt] += __shfl_xor(lsum[jt], 16);
        lsum[jt] += __shfl_xor(lsum[jt], 32);
    }
    __syncthreads();
#pragma unroll
    for (int mt = 0; mt < 4; mt++)
#pragma unroll
        for (int dt = 0; dt < 4; dt++)
#pragma unroll
            for (int rg = 0; rg < 4; rg++)
                Oshb[w * 4608 + (mt * 16 + lq * 4 + rg) * 72 + dt * 16 + lr] =
                    f2b(oacc[mt][dt][rg]);
    if (lq == 0)
#pragma unroll
        for (int jt = 0; jt < 4; jt++) Lsh[w * 64 + jt * 16 + lr] = lsum[jt];
    __syncthreads();
    int m = tid >> 2, dg = (tid & 3) * 16;
    float l = Lsh[m] + Lsh[64 + m] + Lsh[128 + m] + Lsh[192 + m];
    float inv = 1.0f / l;
    float r[16];
#pragma unroll
    for (int i = 0; i < 16; i++) r[i] = 0.f;
#pragma unroll
    for (int ww = 0; ww < 4; ww++) {
        const short8* op = (const short8*)&Oshb[ww * 4608 + m * 72 + dg];
        short8 a = op[0], bq = op[1];
#pragma unroll
        for (int i = 0; i < 8; i++) { r[i] += b2f(a[i]); r[8 + i] += b2f(bq[i]); }
    }
    short8 o0, o1;
#pragma unroll
    for (int i = 0; i < 8; i++) { o0[i] = f2b(r[i] * inv); o1[i] = f2b(r[8 + i] * inv); }
    int b = bh >> 3, h = bh & 7;
    long base = ((long)(b * 1024 + qb * 64 + m)) * 512 + h * 64 + dg;
    *(short8*)(out + base) = o0;
    *(short8*)(out + base + 8) = o1;
}

// ---------------- depthwise 3x3 conv + bias + exact GeLU -----------------------
__global__ __launch_bounds__(256) void dwconv_gelu(
    const short* __restrict__ h1, const float* __restrict__ wdT,
    const float* __restrict__ bias, short* __restrict__ h2) {
    int bn = blockIdx.x;                  // (b, n)
    int b = bn >> 10, n = bn & 1023;
    int yy = n >> 5, xx = n & 31;
    int c0 = threadIdx.x * 8;
    float4 bv0 = ((const float4*)&bias[c0])[0];
    float4 bv1 = ((const float4*)&bias[c0])[1];
    float acc[8] = {bv0.x, bv0.y, bv0.z, bv0.w, bv1.x, bv1.y, bv1.z, bv1.w};
    for (int ky = 0; ky < 3; ky++) {
        int ys = yy + ky - 1;
        if (ys < 0 || ys > 31) continue;
        for (int kx = 0; kx < 3; kx++) {
            int xs = xx + kx - 1;
            if (xs < 0 || xs > 31) continue;
            short8 hv = *(const short8*)&h1[((long)(b * 1024 + ys * 32 + xs)) * 2048 + c0];
            const float4* wp = (const float4*)&wdT[(ky * 3 + kx) * 2048 + c0];
            float4 wa = wp[0], wb = wp[1];
            float wv[8] = {wa.x, wa.y, wa.z, wa.w, wb.x, wb.y, wb.z, wb.w};
#pragma unroll
            for (int e = 0; e < 8; e++)
                acc[e] += b2f(hv[e]) * wv[e];
        }
    }
    short8 o;
#pragma unroll
    for (int e = 0; e < 8; e++) {
        float a = acc[e];
        o[e] = f2b(0.5f * a * (1.0f + erff(a * 0.70710678118f)));
    }
    *(short8*)&h2[((long)bn) * 2048 + c0] = o;
}

// ---------------- driver --------------------------------------------------------
extern "C" void kernel_launch(void* const* d_in, const int* in_sizes, int n_in,
                              void* d_out, int out_size, void* d_ws, size_t ws_size,
                              hipStream_t stream) {
    const float* x      = (const float*)d_in[0];
    const float* ln1_g  = (const float*)d_in[1];
    const float* ln1_b  = (const float*)d_in[2];
    const float* qkv_w  = (const float*)d_in[3];
    const float* proj_w = (const float*)d_in[4];
    const float* proj_b = (const float*)d_in[5];
    const float* ln2_g  = (const float*)d_in[6];
    const float* ln2_b  = (const float*)d_in[7];
    const float* fc1_w  = (const float*)d_in[8];
    const float* fc1_b  = (const float*)d_in[9];
    const float* dw_w   = (const float*)d_in[10];
    const float* dw_b   = (const float*)d_in[11];
    const float* fc2_w  = (const float*)d_in[12];
    const float* fc2_b  = (const float*)d_in[13];
    float* out = (float*)d_out;

    char* p = (char*)d_ws;
    short* wq   = (short*)p; p += (long)1536 * 512 * 2;
    short* wp   = (short*)p; p += (long)512 * 512 * 2;
    short* w1   = (short*)p; p += (long)2048 * 512 * 2;
    short* w2   = (short*)p; p += (long)512 * 2048 * 2;
    float* wdT  = (float*)p; p += (long)9 * 2048 * 4;
    short* y1   = (short*)p; p += (long)8192 * 512 * 2;
    short* q    = (short*)p; p += (long)64 * 1024 * 64 * 2;
    short* k    = (short*)p; p += (long)64 * 1024 * 64 * 2;
    short* vt   = (short*)p; p += (long)64 * 64 * 1024 * 2;
    short* attn = (short*)p; p += (long)8192 * 512 * 2;
    float* x1   = (float*)p; p += (long)8192 * 512 * 4;
    short* y2   = (short*)p; p += (long)8192 * 512 * 2;
    short* h1   = (short*)p; p += (long)8192 * 2048 * 2;
    short* h2   = (short*)p; p += (long)8192 * 2048 * 2;
    if ((size_t)(p - (char*)d_ws) > ws_size) return;  // ws too small: fail loudly

    cvt_weights<<<3072, 256, 0, stream>>>(qkv_w, proj_w, fc1_w, fc2_w, wq, wp, w1, w2);
    cvt_dw<<<72, 256, 0, stream>>>(dw_w, wdT);
    ln_kernel<<<2048, 256, 0, stream>>>(x, ln1_g, ln1_b, y1);
    gemm_bt<128><<<dim3(64, 12), 256, 0, stream>>>(y1, wq, 512, EpiQKV{q, k, vt});
    attn_kernel<<<dim3(64, 16), 256, 0, stream>>>(q, k, vt, attn);
    gemm_bt<64><<<dim3(128, 4), 256, 0, stream>>>(attn, wp, 512,
                                                  EpiProj{proj_b, x, x1});
    ln_kernel<<<2048, 256, 0, stream>>>(x1, ln2_g, ln2_b, y2);
    gemm_bt<128><<<dim3(64, 16), 256, 0, stream>>>(y2, w1, 512,
                                                   EpiBias{fc1_b, h1, 2048});
    dwconv_gelu<<<8192, 256, 0, stream>>>(h1, wdT, dw_b, h2);
    gemm_bt<64><<<dim3(128, 4), 256, 0, stream>>>(h2, w2, 2048,
                                                  EpiFc2{fc2_b, x1, out});
}

// Round 7
// 286.844 us; speedup vs baseline: 1.2958x; 1.0355x over previous
//
#include <hip/hip_runtime.h>
#include <hip/hip_bf16.h>

// Transformer block: x += attn(LN1(x)); x += mlp(LN2(x))
// B=8, N=1024, C=512, H=8 heads, d=64, HID=2048, spatial 32x32.
// R2: dwconv tap-major. R3: fused attention. R4: XOR swizzle -> 0 conflicts.
// R5 lesson: split-K atomics = 4x write amp, loss. R6: proj/fc2 64x128 tiles
// (2 blocks/CU TLP) -> 297us. R7: BK=64 in all GEMMs: halves barrier-drain
// windows (fc2 64->32 iters), 8-chunk XOR swizzle (slot = chunk ^ (row&7)),
// frags loaded per-ks to keep VGPR < 128 (4 waves/SIMD).

typedef __attribute__((ext_vector_type(8))) short short8;   // 8 x bf16 (4 VGPRs)
typedef __attribute__((ext_vector_type(4))) short s16x4;    // 4 x bf16
typedef __attribute__((ext_vector_type(4))) float f32x4;    // MFMA accum

__device__ __forceinline__ float b2f(short s) {
    union { float f; unsigned u; } z; z.u = ((unsigned)(unsigned short)s) << 16; return z.f;
}
__device__ __forceinline__ short f2b(float f) {  // RNE
    union { float f; unsigned u; } z; z.f = f;
    unsigned r = (z.u + 0x7fffu + ((z.u >> 16) & 1u)) >> 16;
    return (short)r;
}

__device__ __forceinline__ void gload_lds16(const void* g, void* l) {
    // async global->LDS, 16B/lane; LDS dest = wave-uniform base + lane*16
    __builtin_amdgcn_global_load_lds(
        (const __attribute__((address_space(1))) void*)g,
        (__attribute__((address_space(3))) void*)l, 16, 0, 0);
}

// ---------------- weight fp32 -> bf16 convert (all 4 weight mats, one launch) ----
__global__ __launch_bounds__(256) void cvt_weights(
    const float* __restrict__ s0, const float* __restrict__ s1,
    const float* __restrict__ s2, const float* __restrict__ s3,
    short* __restrict__ d0, short* __restrict__ d1,
    short* __restrict__ d2, short* __restrict__ d3) {
    long i = (long)blockIdx.x * 256 + threadIdx.x;  // vec4 index, total 786432
    const float* s; short* d; long off;
    if (i < 196608)      { s = s0; d = d0; off = i; }
    else if (i < 262144) { s = s1; d = d1; off = i - 196608; }
    else if (i < 524288) { s = s2; d = d2; off = i - 262144; }
    else                 { s = s3; d = d3; off = i - 524288; }
    float4 v = ((const float4*)s)[off];
    ushort4 o;
    o.x = (unsigned short)f2b(v.x); o.y = (unsigned short)f2b(v.y);
    o.z = (unsigned short)f2b(v.z); o.w = (unsigned short)f2b(v.w);
    ((ushort4*)d)[off] = o;
}

// ---------------- dw_w [2048][9] -> tap-major [9][2048] fp32 -------------------
__global__ __launch_bounds__(256) void cvt_dw(
    const float* __restrict__ src, float* __restrict__ dst) {
    int i = blockIdx.x * 256 + threadIdx.x;   // 72 blocks -> 18432
    int t = i >> 11, c = i & 2047;
    dst[t * 2048 + c] = src[c * 9 + t];
}

// ---------------- layernorm: fp32 [8192][512] -> bf16, one wave per row --------
__global__ __launch_bounds__(256) void ln_kernel(
    const float* __restrict__ x, const float* __restrict__ g,
    const float* __restrict__ b, short* __restrict__ y) {
    int row  = blockIdx.x * 4 + (threadIdx.x >> 6);
    int lane = threadIdx.x & 63;
    const float* xr = x + (long)row * 512 + lane * 8;
    float4 v0 = ((const float4*)xr)[0];
    float4 v1 = ((const float4*)xr)[1];
    float e0[8] = {v0.x, v0.y, v0.z, v0.w, v1.x, v1.y, v1.z, v1.w};
    float s = 0.f;
#pragma unroll
    for (int e = 0; e < 8; e++) s += e0[e];
#pragma unroll
    for (int d = 1; d < 64; d <<= 1) s += __shfl_xor(s, d);
    float mu = s * (1.0f / 512.0f);
    float q = 0.f;
#pragma unroll
    for (int e = 0; e < 8; e++) { float t = e0[e] - mu; q += t * t; }
#pragma unroll
    for (int d = 1; d < 64; d <<= 1) q += __shfl_xor(q, d);
    float rs = rsqrtf(q * (1.0f / 512.0f) + 1e-5f);
    const float* gp = g + lane * 8;
    const float* bp = b + lane * 8;
    short8 o;
#pragma unroll
    for (int e = 0; e < 8; e++) o[e] = f2b((e0[e] - mu) * rs * gp[e] + bp[e]);
    *(short8*)(y + (long)row * 512 + lane * 8) = o;
}

// ---------------- GEMM: C[r][o] = sum_c A[r][c]*B[o][c], A,B bf16 --------------
// MT x 128 tile, BK=64, 4 waves. MT=128: waves 2x2, 4x4 frags. MT=64: waves
// 1x4 (each 64x32), 4x2 frags (2x grid for TLP-starved shapes). Rows are 64
// shorts (8 chunks of 16B); LDS slot s of row r holds global chunk s^(r&7):
// b128 reads from 16 consecutive rows span 8 slot-quads x2 lanes = 2-way (free).
template <int MT, typename Epi>
__global__ __launch_bounds__(256, 4) void gemm_bt(
    const short* __restrict__ A, const short* __restrict__ B, int K, Epi epi) {
    constexpr int NJ = (MT == 128) ? 4 : 2;   // n-frags per wave
    __shared__ short As[MT * 64];
    __shared__ short Bs[128 * 64];
    int tid = threadIdx.x;
    int lane = tid & 63, w = tid >> 6;
    int lr = lane & 15, lq = lane >> 4;
    int wm = (MT == 128) ? (w & 1) * 64 : 0;
    int wn = (MT == 128) ? (w >> 1) * 64 : w * 32;
    long r0 = (long)blockIdx.x * MT, o0 = (long)blockIdx.y * 128;
    f32x4 acc[4][NJ];
#pragma unroll
    for (int i = 0; i < 4; i++)
#pragma unroll
        for (int j = 0; j < NJ; j++) acc[i][j] = (f32x4){0.f, 0.f, 0.f, 0.f};
    const short* Ab = A + r0 * K;
    const short* Bb = B + o0 * K;
    // staging: thread -> (srow = tid>>3 in 0..31, slot = tid&7); source chunk
    // XOR-swizzled; each round covers 32 rows; LDS dest = waveBase + lane*16.
    int srow = tid >> 3;
    int sc = ((tid & 7) ^ (srow & 7)) * 8;    // element offset of source chunk
    for (int k0 = 0; k0 < K; k0 += 64) {
#pragma unroll
        for (int m = 0; m < MT / 32; m++)
            gload_lds16(Ab + (long)(srow + m * 32) * K + k0 + sc,
                        As + m * 2048 + w * 512);
#pragma unroll
        for (int m = 0; m < 4; m++)
            gload_lds16(Bb + (long)(srow + m * 32) * K + k0 + sc,
                        Bs + m * 2048 + w * 512);
        __syncthreads();
#pragma unroll
        for (int ks = 0; ks < 2; ks++) {
            short8 af[4], bfr[NJ];
#pragma unroll
            for (int i = 0; i < 4; i++) {
                int row = wm + i * 16 + lr;
                int c = ks * 4 + lq;
                af[i] = *(const short8*)&As[row * 64 + ((c ^ (row & 7)) * 8)];
            }
#pragma unroll
            for (int j = 0; j < NJ; j++) {
                int row = wn + j * 16 + lr;
                int c = ks * 4 + lq;
                bfr[j] = *(const short8*)&Bs[row * 64 + ((c ^ (row & 7)) * 8)];
            }
#pragma unroll
            for (int i = 0; i < 4; i++)
#pragma unroll
                for (int j = 0; j < NJ; j++)
                    acc[i][j] = __builtin_amdgcn_mfma_f32_16x16x32_bf16(
                        af[i], bfr[j], acc[i][j], 0, 0, 0);
        }
        __syncthreads();
    }
    // C/D layout: col = lane&15, row = (lane>>4)*4 + reg  [m89/m91 verified]
#pragma unroll
    for (int i = 0; i < 4; i++)
#pragma unroll
        for (int j = 0; j < NJ; j++)
#pragma unroll
            for (int rg = 0; rg < 4; rg++)
                epi((int)(r0 + wm + i * 16 + lq * 4 + rg),
                    (int)(o0 + wn + j * 16 + lr), acc[i][j][rg]);
}

// epilogues
struct EpiQKV {   // scatter qkv -> q[bh][n][d], k[bh][n][d], vt[bh][d][n]
    short *q, *k, *vt;
    __device__ void operator()(int r, int o, float v) const {
        int b = r >> 10, n = r & 1023;
        int h = o / 192, j = o - h * 192;
        int bh = b * 8 + h;
        short bv = f2b(v);
        if (j < 64)        q[((long)bh * 1024 + n) * 64 + j] = bv;
        else if (j < 128)  k[((long)bh * 1024 + n) * 64 + (j - 64)] = bv;
        else               vt[((long)bh * 64 + (j - 128)) * 1024 + n] = bv;
    }
};
struct EpiProj {  // x1 = acc + proj_b + x   (fp32)
    const float* pb; const float* x; float* x1;
    __device__ void operator()(int r, int o, float v) const {
        long idx = (long)r * 512 + o;
        x1[idx] = v + pb[o] + x[idx];
    }
};
struct EpiBias {  // h1 = bf16(acc + bias)
    const float* bias; short* out; int O;
    __device__ void operator()(int r, int o, float v) const {
        out[(long)r * O + o] = f2b(v + bias[o]);
    }
};
struct EpiFc2 {   // out = acc + fc2_b + x1  (fp32)
    const float* bias; const float* x1; float* out;
    __device__ void operator()(int r, int o, float v) const {
        long idx = (long)r * 512 + o;
        out[idx] = v + bias[o] + x1[idx];
    }
};

// ---------------- fused attention (R3 structure, unchanged) --------------------
__global__ __launch_bounds__(256, 2) void attn_kernel(
    const short* __restrict__ Q, const short* __restrict__ K,
    const short* __restrict__ Vt, short* __restrict__ out) {
    __shared__ __align__(16) char smem[53248];
    int bh = blockIdx.x, qb = blockIdx.y;
    int tid = threadIdx.x, w = tid >> 6, lane = tid & 63;
    int lr = lane & 15, lq = lane >> 4;
    short* Kt = (short*)(smem + w * 13312);
    short* Vl = (short*)(smem + w * 13312 + 4096);
    short* Pt = (short*)(smem + w * 13312 + 8192);
    short* Oshb = (short*)smem;                    // 36864 B
    float* Lsh  = (float*)(smem + 36864);          // 1024 B

    const short* Qb = Q + ((long)bh * 1024 + qb * 64) * 64;
    const short* Kb = K + (long)bh * 1024 * 64;
    const short* Vb = Vt + (long)bh * 64 * 1024;

    short8 qf[4][2];
#pragma unroll
    for (int jt = 0; jt < 4; jt++)
#pragma unroll
        for (int ks = 0; ks < 2; ks++)
            qf[jt][ks] = *(const short8*)(Qb + (jt * 16 + lr) * 64 + ks * 32 + lq * 8);

    f32x4 oacc[4][4];
#pragma unroll
    for (int mt = 0; mt < 4; mt++)
#pragma unroll
        for (int dt = 0; dt < 4; dt++) oacc[mt][dt] = (f32x4){0.f, 0.f, 0.f, 0.f};
    float lsum[4] = {0.f, 0.f, 0.f, 0.f};

    for (int it = 0; it < 8; it++) {
        int n0 = w * 256 + it * 32;
#pragma unroll
        for (int i = 0; i < 4; i++) {
            int s = i * 64 + lane;
            int row = s >> 3, ch = (s & 7) ^ (row & 7);
            gload_lds16(Kb + (long)(n0 + row) * 64 + ch * 8, Kt + i * 512);
        }
#pragma unroll
        for (int i = 0; i < 4; i++) {
            int s = i * 64 + lane;
            int row = s >> 2, ch = s & 3;
            gload_lds16(Vb + (long)row * 1024 + n0 + ch * 8, Vl + i * 512);
        }
        asm volatile("s_waitcnt vmcnt(0)" ::: "memory");
        f32x4 sacc[2][4];
#pragma unroll
        for (int kt = 0; kt < 2; kt++)
#pragma unroll
            for (int jt = 0; jt < 4; jt++) sacc[kt][jt] = (f32x4){0.f, 0.f, 0.f, 0.f};
#pragma unroll
        for (int ks = 0; ks < 2; ks++)
#pragma unroll
            for (int kt = 0; kt < 2; kt++) {
                short8 ak = *(const short8*)&Kt[(kt * 16 + lr) * 64 +
                                                (((ks * 4 + lq) ^ (lr & 7)) * 8)];
#pragma unroll
                for (int jt = 0; jt < 4; jt++)
                    sacc[kt][jt] = __builtin_amdgcn_mfma_f32_16x16x32_bf16(
                        ak, qf[jt][ks], sacc[kt][jt], 0, 0, 0);
            }
#pragma unroll
        for (int kt = 0; kt < 2; kt++)
#pragma unroll
            for (int jt = 0; jt < 4; jt++) {
                s16x4 pv;
#pragma unroll
                for (int rg = 0; rg < 4; rg++) {
                    float e = __expf(sacc[kt][jt][rg] * 0.125f);
                    lsum[jt] += e;
                    pv[rg] = f2b(e);
                }
                *(s16x4*)&Pt[(jt * 16 + lr) * 40 + kt * 16 + lq * 4] = pv;
            }
        short8 bv[4];
#pragma unroll
        for (int dt = 0; dt < 4; dt++)
            bv[dt] = *(const short8*)&Vl[(dt * 16 + lr) * 32 + lq * 8];
#pragma unroll
        for (int mt = 0; mt < 4; mt++) {
            short8 ap = *(const short8*)&Pt[(mt * 16 + lr) * 40 + lq * 8];
#pragma unroll
            for (int dt = 0; dt < 4; dt++)
                oacc[mt][dt] = __builtin_amdgcn_mfma_f32_16x16x32_bf16(
                    ap, bv[dt], oacc[mt][dt], 0, 0, 0);
        }
    }
#pragma unroll
    for (int jt = 0; jt < 4; jt++) {
        lsum[jt] += __shfl_xor(lsum[jt], 16);
        lsum[jt] += __shfl_xor(lsum[jt], 32);
    }
    __syncthreads();
#pragma unroll
    for (int mt = 0; mt < 4; mt++)
#pragma unroll
        for (int dt = 0; dt < 4; dt++)
#pragma unroll
            for (int rg = 0; rg < 4; rg++)
                Oshb[w * 4608 + (mt * 16 + lq * 4 + rg) * 72 + dt * 16 + lr] =
                    f2b(oacc[mt][dt][rg]);
    if (lq == 0)
#pragma unroll
        for (int jt = 0; jt < 4; jt++) Lsh[w * 64 + jt * 16 + lr] = lsum[jt];
    __syncthreads();
    int m = tid >> 2, dg = (tid & 3) * 16;
    float l = Lsh[m] + Lsh[64 + m] + Lsh[128 + m] + Lsh[192 + m];
    float inv = 1.0f / l;
    float r[16];
#pragma unroll
    for (int i = 0; i < 16; i++) r[i] = 0.f;
#pragma unroll
    for (int ww = 0; ww < 4; ww++) {
        const short8* op = (const short8*)&Oshb[ww * 4608 + m * 72 + dg];
        short8 a = op[0], bq = op[1];
#pragma unroll
        for (int i = 0; i < 8; i++) { r[i] += b2f(a[i]); r[8 + i] += b2f(bq[i]); }
    }
    short8 o0, o1;
#pragma unroll
    for (int i = 0; i < 8; i++) { o0[i] = f2b(r[i] * inv); o1[i] = f2b(r[8 + i] * inv); }
    int b = bh >> 3, h = bh & 7;
    long base = ((long)(b * 1024 + qb * 64 + m)) * 512 + h * 64 + dg;
    *(short8*)(out + base) = o0;
    *(short8*)(out + base + 8) = o1;
}

// ---------------- depthwise 3x3 conv + bias + exact GeLU -----------------------
__global__ __launch_bounds__(256) void dwconv_gelu(
    const short* __restrict__ h1, const float* __restrict__ wdT,
    const float* __restrict__ bias, short* __restrict__ h2) {
    int bn = blockIdx.x;                  // (b, n)
    int b = bn >> 10, n = bn & 1023;
    int yy = n >> 5, xx = n & 31;
    int c0 = threadIdx.x * 8;
    float4 bv0 = ((const float4*)&bias[c0])[0];
    float4 bv1 = ((const float4*)&bias[c0])[1];
    float acc[8] = {bv0.x, bv0.y, bv0.z, bv0.w, bv1.x, bv1.y, bv1.z, bv1.w};
    for (int ky = 0; ky < 3; ky++) {
        int ys = yy + ky - 1;
        if (ys < 0 || ys > 31) continue;
        for (int kx = 0; kx < 3; kx++) {
            int xs = xx + kx - 1;
            if (xs < 0 || xs > 31) continue;
            short8 hv = *(const short8*)&h1[((long)(b * 1024 + ys * 32 + xs)) * 2048 + c0];
            const float4* wp = (const float4*)&wdT[(ky * 3 + kx) * 2048 + c0];
            float4 wa = wp[0], wb = wp[1];
            float wv[8] = {wa.x, wa.y, wa.z, wa.w, wb.x, wb.y, wb.z, wb.w};
#pragma unroll
            for (int e = 0; e < 8; e++)
                acc[e] += b2f(hv[e]) * wv[e];
        }
    }
    short8 o;
#pragma unroll
    for (int e = 0; e < 8; e++) {
        float a = acc[e];
        o[e] = f2b(0.5f * a * (1.0f + erff(a * 0.70710678118f)));
    }
    *(short8*)&h2[((long)bn) * 2048 + c0] = o;
}

// ---------------- driver --------------------------------------------------------
extern "C" void kernel_launch(void* const* d_in, const int* in_sizes, int n_in,
                              void* d_out, int out_size, void* d_ws, size_t ws_size,
                              hipStream_t stream) {
    const float* x      = (const float*)d_in[0];
    const float* ln1_g  = (const float*)d_in[1];
    const float* ln1_b  = (const float*)d_in[2];
    const float* qkv_w  = (const float*)d_in[3];
    const float* proj_w = (const float*)d_in[4];
    const float* proj_b = (const float*)d_in[5];
    const float* ln2_g  = (const float*)d_in[6];
    const float* ln2_b  = (const float*)d_in[7];
    const float* fc1_w  = (const float*)d_in[8];
    const float* fc1_b  = (const float*)d_in[9];
    const float* dw_w   = (const float*)d_in[10];
    const float* dw_b   = (const float*)d_in[11];
    const float* fc2_w  = (const float*)d_in[12];
    const float* fc2_b  = (const float*)d_in[13];
    float* out = (float*)d_out;

    char* p = (char*)d_ws;
    short* wq   = (short*)p; p += (long)1536 * 512 * 2;
    short* wp   = (short*)p; p += (long)512 * 512 * 2;
    short* w1   = (short*)p; p += (long)2048 * 512 * 2;
    short* w2   = (short*)p; p += (long)512 * 2048 * 2;
    float* wdT  = (float*)p; p += (long)9 * 2048 * 4;
    short* y1   = (short*)p; p += (long)8192 * 512 * 2;
    short* q    = (short*)p; p += (long)64 * 1024 * 64 * 2;
    short* k    = (short*)p; p += (long)64 * 1024 * 64 * 2;
    short* vt   = (short*)p; p += (long)64 * 64 * 1024 * 2;
    short* attn = (short*)p; p += (long)8192 * 512 * 2;
    float* x1   = (float*)p; p += (long)8192 * 512 * 4;
    short* y2   = (short*)p; p += (long)8192 * 512 * 2;
    short* h1   = (short*)p; p += (long)8192 * 2048 * 2;
    short* h2   = (short*)p; p += (long)8192 * 2048 * 2;
    if ((size_t)(p - (char*)d_ws) > ws_size) return;  // ws too small: fail loudly

    cvt_weights<<<3072, 256, 0, stream>>>(qkv_w, proj_w, fc1_w, fc2_w, wq, wp, w1, w2);
    cvt_dw<<<72, 256, 0, stream>>>(dw_w, wdT);
    ln_kernel<<<2048, 256, 0, stream>>>(x, ln1_g, ln1_b, y1);
    gemm_bt<128><<<dim3(64, 12), 256, 0, stream>>>(y1, wq, 512, EpiQKV{q, k, vt});
    attn_kernel<<<dim3(64, 16), 256, 0, stream>>>(q, k, vt, attn);
    gemm_bt<64><<<dim3(128, 4), 256, 0, stream>>>(attn, wp, 512,
                                                  EpiProj{proj_b, x, x1});
    ln_kernel<<<2048, 256, 0, stream>>>(x1, ln2_g, ln2_b, y2);
    gemm_bt<128><<<dim3(64, 16), 256, 0, stream>>>(y2, w1, 512,
                                                   EpiBias{fc1_b, h1, 2048});
    dwconv_gelu<<<8192, 256, 0, stream>>>(h1, wdT, dw_b, h2);
    gemm_bt<64><<<dim3(128, 4), 256, 0, stream>>>(h2, w2, 2048,
                                                  EpiFc2{fc2_b, x1, out});
}

// Round 8
// 274.438 us; speedup vs baseline: 1.3544x; 1.0452x over previous
//
#include <hip/hip_runtime.h>
#include <hip/hip_bf16.h>

// Transformer block: x += attn(LN1(x)); x += mlp(LN2(x))
// B=8, N=1024, C=512, H=8 heads, d=64, HID=2048, spatial 32x32.
// R2: dwconv tap-major. R3: fused attention. R4: XOR swizzle -> 0 conflicts.
// R5: split-K atomics = write amp, loss. R6: proj/fc2 64x128 tiles (TLP).
// R7: BK=64 -> 287us. R8: dwconv row-tiled sliding window + rational erf
// (VALU/elem 75->34, loads/elem 9->~1); attn: P stride 36 (conflict-free),
// truncation-pack P, 3 blocks/CU.

typedef __attribute__((ext_vector_type(8))) short short8;   // 8 x bf16 (4 VGPRs)
typedef __attribute__((ext_vector_type(4))) short s16x4;    // 4 x bf16
typedef __attribute__((ext_vector_type(4))) float f32x4;    // MFMA accum

__device__ __forceinline__ float b2f(short s) {
    union { float f; unsigned u; } z; z.u = ((unsigned)(unsigned short)s) << 16; return z.f;
}
__device__ __forceinline__ short f2b(float f) {  // RNE
    union { float f; unsigned u; } z; z.f = f;
    unsigned r = (z.u + 0x7fffu + ((z.u >> 16) & 1u)) >> 16;
    return (short)r;
}
__device__ __forceinline__ float erf_fast(float x) {  // A&S 7.1.26, |err|<1.5e-7
    float ax = fabsf(x);
    float t = 1.0f / fmaf(0.3275911f, ax, 1.0f);
    float p = t * fmaf(t, fmaf(t, fmaf(t, fmaf(t, 1.061405429f, -1.453152027f),
                        1.421413741f), -0.284496736f), 0.254829592f);
    float r = 1.0f - p * __expf(-ax * ax);
    return x < 0.f ? -r : r;
}

__device__ __forceinline__ void gload_lds16(const void* g, void* l) {
    // async global->LDS, 16B/lane; LDS dest = wave-uniform base + lane*16
    __builtin_amdgcn_global_load_lds(
        (const __attribute__((address_space(1))) void*)g,
        (__attribute__((address_space(3))) void*)l, 16, 0, 0);
}

// ---------------- weight fp32 -> bf16 convert (all 4 weight mats, one launch) ----
__global__ __launch_bounds__(256) void cvt_weights(
    const float* __restrict__ s0, const float* __restrict__ s1,
    const float* __restrict__ s2, const float* __restrict__ s3,
    short* __restrict__ d0, short* __restrict__ d1,
    short* __restrict__ d2, short* __restrict__ d3) {
    long i = (long)blockIdx.x * 256 + threadIdx.x;  // vec4 index, total 786432
    const float* s; short* d; long off;
    if (i < 196608)      { s = s0; d = d0; off = i; }
    else if (i < 262144) { s = s1; d = d1; off = i - 196608; }
    else if (i < 524288) { s = s2; d = d2; off = i - 262144; }
    else                 { s = s3; d = d3; off = i - 524288; }
    float4 v = ((const float4*)s)[off];
    ushort4 o;
    o.x = (unsigned short)f2b(v.x); o.y = (unsigned short)f2b(v.y);
    o.z = (unsigned short)f2b(v.z); o.w = (unsigned short)f2b(v.w);
    ((ushort4*)d)[off] = o;
}

// ---------------- dw_w [2048][9] -> tap-major [9][2048] fp32 -------------------
__global__ __launch_bounds__(256) void cvt_dw(
    const float* __restrict__ src, float* __restrict__ dst) {
    int i = blockIdx.x * 256 + threadIdx.x;   // 72 blocks -> 18432
    int t = i >> 11, c = i & 2047;
    dst[t * 2048 + c] = src[c * 9 + t];
}

// ---------------- layernorm: fp32 [8192][512] -> bf16, one wave per row --------
__global__ __launch_bounds__(256) void ln_kernel(
    const float* __restrict__ x, const float* __restrict__ g,
    const float* __restrict__ b, short* __restrict__ y) {
    int row  = blockIdx.x * 4 + (threadIdx.x >> 6);
    int lane = threadIdx.x & 63;
    const float* xr = x + (long)row * 512 + lane * 8;
    float4 v0 = ((const float4*)xr)[0];
    float4 v1 = ((const float4*)xr)[1];
    float e0[8] = {v0.x, v0.y, v0.z, v0.w, v1.x, v1.y, v1.z, v1.w};
    float s = 0.f;
#pragma unroll
    for (int e = 0; e < 8; e++) s += e0[e];
#pragma unroll
    for (int d = 1; d < 64; d <<= 1) s += __shfl_xor(s, d);
    float mu = s * (1.0f / 512.0f);
    float q = 0.f;
#pragma unroll
    for (int e = 0; e < 8; e++) { float t = e0[e] - mu; q += t * t; }
#pragma unroll
    for (int d = 1; d < 64; d <<= 1) q += __shfl_xor(q, d);
    float rs = rsqrtf(q * (1.0f / 512.0f) + 1e-5f);
    const float* gp = g + lane * 8;
    const float* bp = b + lane * 8;
    short8 o;
#pragma unroll
    for (int e = 0; e < 8; e++) o[e] = f2b((e0[e] - mu) * rs * gp[e] + bp[e]);
    *(short8*)(y + (long)row * 512 + lane * 8) = o;
}

// ---------------- GEMM: C[r][o] = sum_c A[r][c]*B[o][c], A,B bf16 --------------
// MT x 128 tile, BK=64, 4 waves. MT=128: waves 2x2, 4x4 frags. MT=64: waves
// 1x4 (each 64x32), 4x2 frags (2x grid for TLP-starved shapes). Rows are 64
// shorts (8 chunks of 16B); LDS slot s of row r holds global chunk s^(r&7):
// b128 reads from 16 consecutive rows span 8 slot-quads x2 lanes = 2-way (free).
template <int MT, typename Epi>
__global__ __launch_bounds__(256, 4) void gemm_bt(
    const short* __restrict__ A, const short* __restrict__ B, int K, Epi epi) {
    constexpr int NJ = (MT == 128) ? 4 : 2;   // n-frags per wave
    __shared__ short As[MT * 64];
    __shared__ short Bs[128 * 64];
    int tid = threadIdx.x;
    int lane = tid & 63, w = tid >> 6;
    int lr = lane & 15, lq = lane >> 4;
    int wm = (MT == 128) ? (w & 1) * 64 : 0;
    int wn = (MT == 128) ? (w >> 1) * 64 : w * 32;
    long r0 = (long)blockIdx.x * MT, o0 = (long)blockIdx.y * 128;
    f32x4 acc[4][NJ];
#pragma unroll
    for (int i = 0; i < 4; i++)
#pragma unroll
        for (int j = 0; j < NJ; j++) acc[i][j] = (f32x4){0.f, 0.f, 0.f, 0.f};
    const short* Ab = A + r0 * K;
    const short* Bb = B + o0 * K;
    // staging: thread -> (srow = tid>>3 in 0..31, slot = tid&7); source chunk
    // XOR-swizzled; each round covers 32 rows; LDS dest = waveBase + lane*16.
    int srow = tid >> 3;
    int sc = ((tid & 7) ^ (srow & 7)) * 8;    // element offset of source chunk
    for (int k0 = 0; k0 < K; k0 += 64) {
#pragma unroll
        for (int m = 0; m < MT / 32; m++)
            gload_lds16(Ab + (long)(srow + m * 32) * K + k0 + sc,
                        As + m * 2048 + w * 512);
#pragma unroll
        for (int m = 0; m < 4; m++)
            gload_lds16(Bb + (long)(srow + m * 32) * K + k0 + sc,
                        Bs + m * 2048 + w * 512);
        __syncthreads();
#pragma unroll
        for (int ks = 0; ks < 2; ks++) {
            short8 af[4], bfr[NJ];
#pragma unroll
            for (int i = 0; i < 4; i++) {
                int row = wm + i * 16 + lr;
                int c = ks * 4 + lq;
                af[i] = *(const short8*)&As[row * 64 + ((c ^ (row & 7)) * 8)];
            }
#pragma unroll
            for (int j = 0; j < NJ; j++) {
                int row = wn + j * 16 + lr;
                int c = ks * 4 + lq;
                bfr[j] = *(const short8*)&Bs[row * 64 + ((c ^ (row & 7)) * 8)];
            }
#pragma unroll
            for (int i = 0; i < 4; i++)
#pragma unroll
                for (int j = 0; j < NJ; j++)
                    acc[i][j] = __builtin_amdgcn_mfma_f32_16x16x32_bf16(
                        af[i], bfr[j], acc[i][j], 0, 0, 0);
        }
        __syncthreads();
    }
    // C/D layout: col = lane&15, row = (lane>>4)*4 + reg  [m89/m91 verified]
#pragma unroll
    for (int i = 0; i < 4; i++)
#pragma unroll
        for (int j = 0; j < NJ; j++)
#pragma unroll
            for (int rg = 0; rg < 4; rg++)
                epi((int)(r0 + wm + i * 16 + lq * 4 + rg),
                    (int)(o0 + wn + j * 16 + lr), acc[i][j][rg]);
}

// epilogues
struct EpiQKV {   // scatter qkv -> q[bh][n][d], k[bh][n][d], vt[bh][d][n]
    short *q, *k, *vt;
    __device__ void operator()(int r, int o, float v) const {
        int b = r >> 10, n = r & 1023;
        int h = o / 192, j = o - h * 192;
        int bh = b * 8 + h;
        short bv = f2b(v);
        if (j < 64)        q[((long)bh * 1024 + n) * 64 + j] = bv;
        else if (j < 128)  k[((long)bh * 1024 + n) * 64 + (j - 64)] = bv;
        else               vt[((long)bh * 64 + (j - 128)) * 1024 + n] = bv;
    }
};
struct EpiProj {  // x1 = acc + proj_b + x   (fp32)
    const float* pb; const float* x; float* x1;
    __device__ void operator()(int r, int o, float v) const {
        long idx = (long)r * 512 + o;
        x1[idx] = v + pb[o] + x[idx];
    }
};
struct EpiBias {  // h1 = bf16(acc + bias)
    const float* bias; short* out; int O;
    __device__ void operator()(int r, int o, float v) const {
        out[(long)r * O + o] = f2b(v + bias[o]);
    }
};
struct EpiFc2 {   // out = acc + fc2_b + x1  (fp32)
    const float* bias; const float* x1; float* out;
    __device__ void operator()(int r, int o, float v) const {
        long idx = (long)r * 512 + o;
        out[idx] = v + bias[o] + x1[idx];
    }
};

// ---------------- fused attention (R3 structure; R8: P stride 36, pack, 3/CU) --
__global__ __launch_bounds__(256, 3) void attn_kernel(
    const short* __restrict__ Q, const short* __restrict__ K,
    const short* __restrict__ Vt, short* __restrict__ out) {
    __shared__ __align__(16) char smem[53248];
    int bh = blockIdx.x, qb = blockIdx.y;
    int tid = threadIdx.x, w = tid >> 6, lane = tid & 63;
    int lr = lane & 15, lq = lane >> 4;
    short* Kt = (short*)(smem + w * 13312);
    short* Vl = (short*)(smem + w * 13312 + 4096);
    short* Pt = (short*)(smem + w * 13312 + 8192);   // 64 rows x 36 = 4608 B
    short* Oshb = (short*)smem;                    // 36864 B
    float* Lsh  = (float*)(smem + 36864);          // 1024 B

    const short* Qb = Q + ((long)bh * 1024 + qb * 64) * 64;
    const short* Kb = K + (long)bh * 1024 * 64;
    const short* Vb = Vt + (long)bh * 64 * 1024;

    short8 qf[4][2];
#pragma unroll
    for (int jt = 0; jt < 4; jt++)
#pragma unroll
        for (int ks = 0; ks < 2; ks++)
            qf[jt][ks] = *(const short8*)(Qb + (jt * 16 + lr) * 64 + ks * 32 + lq * 8);

    f32x4 oacc[4][4];
#pragma unroll
    for (int mt = 0; mt < 4; mt++)
#pragma unroll
        for (int dt = 0; dt < 4; dt++) oacc[mt][dt] = (f32x4){0.f, 0.f, 0.f, 0.f};
    float lsum[4] = {0.f, 0.f, 0.f, 0.f};

    for (int it = 0; it < 8; it++) {
        int n0 = w * 256 + it * 32;
#pragma unroll
        for (int i = 0; i < 4; i++) {
            int s = i * 64 + lane;
            int row = s >> 3, ch = (s & 7) ^ (row & 7);
            gload_lds16(Kb + (long)(n0 + row) * 64 + ch * 8, Kt + i * 512);
        }
#pragma unroll
        for (int i = 0; i < 4; i++) {
            int s = i * 64 + lane;
            int row = s >> 2, ch = s & 3;
            gload_lds16(Vb + (long)row * 1024 + n0 + ch * 8, Vl + i * 512);
        }
        asm volatile("s_waitcnt vmcnt(0)" ::: "memory");
        f32x4 sacc[2][4];
#pragma unroll
        for (int kt = 0; kt < 2; kt++)
#pragma unroll
            for (int jt = 0; jt < 4; jt++) sacc[kt][jt] = (f32x4){0.f, 0.f, 0.f, 0.f};
#pragma unroll
        for (int ks = 0; ks < 2; ks++)
#pragma unroll
            for (int kt = 0; kt < 2; kt++) {
                short8 ak = *(const short8*)&Kt[(kt * 16 + lr) * 64 +
                                                (((ks * 4 + lq) ^ (lr & 7)) * 8)];
#pragma unroll
                for (int jt = 0; jt < 4; jt++)
                    sacc[kt][jt] = __builtin_amdgcn_mfma_f32_16x16x32_bf16(
                        ak, qf[jt][ks], sacc[kt][jt], 0, 0, 0);
            }
        // exp(s/8); in-lane l partial; truncation-pack 2xbf16/dword -> Pt
#pragma unroll
        for (int kt = 0; kt < 2; kt++)
#pragma unroll
            for (int jt = 0; jt < 4; jt++) {
                float e0 = __expf(sacc[kt][jt][0] * 0.125f);
                float e1 = __expf(sacc[kt][jt][1] * 0.125f);
                float e2 = __expf(sacc[kt][jt][2] * 0.125f);
                float e3 = __expf(sacc[kt][jt][3] * 0.125f);
                lsum[jt] += (e0 + e1) + (e2 + e3);
                uint2 pk;
                pk.x = (__float_as_uint(e1) & 0xffff0000u) | (__float_as_uint(e0) >> 16);
                pk.y = (__float_as_uint(e3) & 0xffff0000u) | (__float_as_uint(e2) >> 16);
                *(uint2*)&Pt[(jt * 16 + lr) * 36 + kt * 16 + lq * 4] = pk;
            }
        short8 bv[4];
#pragma unroll
        for (int dt = 0; dt < 4; dt++)
            bv[dt] = *(const short8*)&Vl[(dt * 16 + lr) * 32 + lq * 8];
#pragma unroll
        for (int mt = 0; mt < 4; mt++) {
            short8 ap = *(const short8*)&Pt[(mt * 16 + lr) * 36 + lq * 8];
#pragma unroll
            for (int dt = 0; dt < 4; dt++)
                oacc[mt][dt] = __builtin_amdgcn_mfma_f32_16x16x32_bf16(
                    ap, bv[dt], oacc[mt][dt], 0, 0, 0);
        }
    }
#pragma unroll
    for (int jt = 0; jt < 4; jt++) {
        lsum[jt] += __shfl_xor(lsum[jt], 16);
        lsum[jt] += __shfl_xor(lsum[jt], 32);
    }
    __syncthreads();
#pragma unroll
    for (int mt = 0; mt < 4; mt++)
#pragma unroll
        for (int dt = 0; dt < 4; dt++)
#pragma unroll
            for (int rg = 0; rg < 4; rg++)
                Oshb[w * 4608 + (mt * 16 + lq * 4 + rg) * 72 + dt * 16 + lr] =
                    f2b(oacc[mt][dt][rg]);
    if (lq == 0)
#pragma unroll
        for (int jt = 0; jt < 4; jt++) Lsh[w * 64 + jt * 16 + lr] = lsum[jt];
    __syncthreads();
    int m = tid >> 2, dg = (tid & 3) * 16;
    float l = Lsh[m] + Lsh[64 + m] + Lsh[128 + m] + Lsh[192 + m];
    float inv = 1.0f / l;
    float r[16];
#pragma unroll
    for (int i = 0; i < 16; i++) r[i] = 0.f;
#pragma unroll
    for (int ww = 0; ww < 4; ww++) {
        const short8* op = (const short8*)&Oshb[ww * 4608 + m * 72 + dg];
        short8 a = op[0], bq = op[1];
#pragma unroll
        for (int i = 0; i < 8; i++) { r[i] += b2f(a[i]); r[8 + i] += b2f(bq[i]); }
    }
    short8 o0, o1;
#pragma unroll
    for (int i = 0; i < 8; i++) { o0[i] = f2b(r[i] * inv); o1[i] = f2b(r[8 + i] * inv); }
    int b = bh >> 3, h = bh & 7;
    long base = ((long)(b * 1024 + qb * 64 + m)) * 512 + h * 64 + dg;
    *(short8*)(out + base) = o0;
    *(short8*)(out + base + 8) = o1;
}

// ---------------- depthwise 3x3 conv + bias + exact GeLU (R8 row-tiled) --------
// Block = (b, yy, x-octet, ch-half); thread = 4 channels x 8 x-positions.
// Sliding 3-col window, convert-on-load: each input col loaded once per ky
// (30 loads / 32 outputs vs 9/output before). Rational erf (~14 ops).
__global__ __launch_bounds__(256, 3) void dwconv_gelu(
    const short* __restrict__ h1, const float* __restrict__ wdT,
    const float* __restrict__ bias, short* __restrict__ h2) {
    int ch = blockIdx.x & 1, xq = (blockIdx.x >> 1) & 3;
    int yy = (blockIdx.x >> 3) & 31, b = blockIdx.x >> 8;
    int c0 = ch * 1024 + threadIdx.x * 4;
    int x0 = xq * 8;
    float w[9][4];
#pragma unroll
    for (int t = 0; t < 9; t++) {
        float4 v = *(const float4*)&wdT[t * 2048 + c0];
        w[t][0] = v.x; w[t][1] = v.y; w[t][2] = v.z; w[t][3] = v.w;
    }
    float4 bv = *(const float4*)&bias[c0];
    float acc[8][4];
#pragma unroll
    for (int xi = 0; xi < 8; xi++) {
        acc[xi][0] = bv.x; acc[xi][1] = bv.y; acc[xi][2] = bv.z; acc[xi][3] = bv.w;
    }
#pragma unroll
    for (int ky = 0; ky < 3; ky++) {
        int ys = yy + ky - 1;
        if (ys < 0 || ys > 31) continue;      // wave-uniform
        const short* rp = h1 + ((long)(b * 1024 + ys * 32) * 2048 + c0);
        float fa[4], fb[4], fc[4];
        if (x0 > 0) {
            s16x4 v = *(const s16x4*)(rp + (long)(x0 - 1) * 2048);
#pragma unroll
            for (int e = 0; e < 4; e++) fa[e] = b2f(v[e]);
        } else {
#pragma unroll
            for (int e = 0; e < 4; e++) fa[e] = 0.f;
        }
        {
            s16x4 v = *(const s16x4*)(rp + (long)x0 * 2048);
#pragma unroll
            for (int e = 0; e < 4; e++) fb[e] = b2f(v[e]);
        }
#pragma unroll
        for (int xi = 0; xi < 8; xi++) {
            int xs = x0 + xi + 1;
            if (xs <= 31) {
                s16x4 v = *(const s16x4*)(rp + (long)xs * 2048);
#pragma unroll
                for (int e = 0; e < 4; e++) fc[e] = b2f(v[e]);
            } else {
#pragma unroll
                for (int e = 0; e < 4; e++) fc[e] = 0.f;
            }
#pragma unroll
            for (int e = 0; e < 4; e++)
                acc[xi][e] += fa[e] * w[ky * 3][e] + fb[e] * w[ky * 3 + 1][e] +
                              fc[e] * w[ky * 3 + 2][e];
#pragma unroll
            for (int e = 0; e < 4; e++) { fa[e] = fb[e]; fb[e] = fc[e]; }
        }
    }
#pragma unroll
    for (int xi = 0; xi < 8; xi++) {
        s16x4 o;
#pragma unroll
        for (int e = 0; e < 4; e++) {
            float a = acc[xi][e];
            o[e] = f2b(0.5f * a * (1.0f + erf_fast(a * 0.70710678118f)));
        }
        *(s16x4*)&h2[(long)(b * 1024 + yy * 32 + x0 + xi) * 2048 + c0] = o;
    }
}

// ---------------- driver --------------------------------------------------------
extern "C" void kernel_launch(void* const* d_in, const int* in_sizes, int n_in,
                              void* d_out, int out_size, void* d_ws, size_t ws_size,
                              hipStream_t stream) {
    const float* x      = (const float*)d_in[0];
    const float* ln1_g  = (const float*)d_in[1];
    const float* ln1_b  = (const float*)d_in[2];
    const float* qkv_w  = (const float*)d_in[3];
    const float* proj_w = (const float*)d_in[4];
    const float* proj_b = (const float*)d_in[5];
    const float* ln2_g  = (const float*)d_in[6];
    const float* ln2_b  = (const float*)d_in[7];
    const float* fc1_w  = (const float*)d_in[8];
    const float* fc1_b  = (const float*)d_in[9];
    const float* dw_w   = (const float*)d_in[10];
    const float* dw_b   = (const float*)d_in[11];
    const float* fc2_w  = (const float*)d_in[12];
    const float* fc2_b  = (const float*)d_in[13];
    float* out = (float*)d_out;

    char* p = (char*)d_ws;
    short* wq   = (short*)p; p += (long)1536 * 512 * 2;
    short* wp   = (short*)p; p += (long)512 * 512 * 2;
    short* w1   = (short*)p; p += (long)2048 * 512 * 2;
    short* w2   = (short*)p; p += (long)512 * 2048 * 2;
    float* wdT  = (float*)p; p += (long)9 * 2048 * 4;
    short* y1   = (short*)p; p += (long)8192 * 512 * 2;
    short* q    = (short*)p; p += (long)64 * 1024 * 64 * 2;
    short* k    = (short*)p; p += (long)64 * 1024 * 64 * 2;
    short* vt   = (short*)p; p += (long)64 * 64 * 1024 * 2;
    short* attn = (short*)p; p += (long)8192 * 512 * 2;
    float* x1   = (float*)p; p += (long)8192 * 512 * 4;
    short* y2   = (short*)p; p += (long)8192 * 512 * 2;
    short* h1   = (short*)p; p += (long)8192 * 2048 * 2;
    short* h2   = (short*)p; p += (long)8192 * 2048 * 2;
    if ((size_t)(p - (char*)d_ws) > ws_size) return;  // ws too small: fail loudly

    cvt_weights<<<3072, 256, 0, stream>>>(qkv_w, proj_w, fc1_w, fc2_w, wq, wp, w1, w2);
    cvt_dw<<<72, 256, 0, stream>>>(dw_w, wdT);
    ln_kernel<<<2048, 256, 0, stream>>>(x, ln1_g, ln1_b, y1);
    gemm_bt<128><<<dim3(64, 12), 256, 0, stream>>>(y1, wq, 512, EpiQKV{q, k, vt});
    attn_kernel<<<dim3(64, 16), 256, 0, stream>>>(q, k, vt, attn);
    gemm_bt<64><<<dim3(128, 4), 256, 0, stream>>>(attn, wp, 512,
                                                  EpiProj{proj_b, x, x1});
    ln_kernel<<<2048, 256, 0, stream>>>(x1, ln2_g, ln2_b, y2);
    gemm_bt<128><<<dim3(64, 16), 256, 0, stream>>>(y2, w1, 512,
                                                   EpiBias{fc1_b, h1, 2048});
    dwconv_gelu<<<2048, 256, 0, stream>>>(h1, wdT, dw_b, h2);
    gemm_bt<64><<<dim3(128, 4), 256, 0, stream>>>(h2, w2, 2048,
                                                  EpiFc2{fc2_b, x1, out});
}

// Round 10
// 271.481 us; speedup vs baseline: 1.3691x; 1.0109x over previous
//
#include <hip/hip_runtime.h>
#include <hip/hip_bf16.h>

// Transformer block: x += attn(LN1(x)); x += mlp(LN2(x))
// B=8, N=1024, C=512, H=8 heads, d=64, HID=2048, spatial 32x32.
// R2: dwconv tap-major. R4: XOR swizzle -> 0 conflicts. R5: split-K atomics =
// write amp, loss. R6: proj/fc2 64x128 tiles (TLP). R7: BK=64. R8: dwconv
// sliding-window + fast erf. R9: attention restructured to shared-tile shape:
// waves split q (16 each), K/V 64-key tiles staged once/block into double
// buffers (prefetch issued post-barrier, waited one iter later -> true
// overlap), no cross-wave merge, P in GEMM-verified XOR-chunk layout,
// 40KB LDS -> 4 blocks/CU, exp2-folded softmax. R9b: no LDS-pointer arrays
// (gfx950 static-initializer addrspacecast unsupported) - ternary offsets.

typedef __attribute__((ext_vector_type(8))) short short8;   // 8 x bf16 (4 VGPRs)
typedef __attribute__((ext_vector_type(4))) short s16x4;    // 4 x bf16
typedef __attribute__((ext_vector_type(4))) float f32x4;    // MFMA accum

__device__ __forceinline__ float b2f(short s) {
    union { float f; unsigned u; } z; z.u = ((unsigned)(unsigned short)s) << 16; return z.f;
}
__device__ __forceinline__ short f2b(float f) {  // RNE
    union { float f; unsigned u; } z; z.f = f;
    unsigned r = (z.u + 0x7fffu + ((z.u >> 16) & 1u)) >> 16;
    return (short)r;
}
__device__ __forceinline__ float erf_fast(float x) {  // A&S 7.1.26, |err|<1.5e-7
    float ax = fabsf(x);
    float t = 1.0f / fmaf(0.3275911f, ax, 1.0f);
    float p = t * fmaf(t, fmaf(t, fmaf(t, fmaf(t, 1.061405429f, -1.453152027f),
                        1.421413741f), -0.284496736f), 0.254829592f);
    float r = 1.0f - p * __expf(-ax * ax);
    return x < 0.f ? -r : r;
}

__device__ __forceinline__ void gload_lds16(const void* g, void* l) {
    // async global->LDS, 16B/lane; LDS dest = wave-uniform base + lane*16
    __builtin_amdgcn_global_load_lds(
        (const __attribute__((address_space(1))) void*)g,
        (__attribute__((address_space(3))) void*)l, 16, 0, 0);
}

// ---------------- weight fp32 -> bf16 convert (all 4 weight mats, one launch) ----
__global__ __launch_bounds__(256) void cvt_weights(
    const float* __restrict__ s0, const float* __restrict__ s1,
    const float* __restrict__ s2, const float* __restrict__ s3,
    short* __restrict__ d0, short* __restrict__ d1,
    short* __restrict__ d2, short* __restrict__ d3) {
    long i = (long)blockIdx.x * 256 + threadIdx.x;  // vec4 index, total 786432
    const float* s; short* d; long off;
    if (i < 196608)      { s = s0; d = d0; off = i; }
    else if (i < 262144) { s = s1; d = d1; off = i - 196608; }
    else if (i < 524288) { s = s2; d = d2; off = i - 262144; }
    else                 { s = s3; d = d3; off = i - 524288; }
    float4 v = ((const float4*)s)[off];
    ushort4 o;
    o.x = (unsigned short)f2b(v.x); o.y = (unsigned short)f2b(v.y);
    o.z = (unsigned short)f2b(v.z); o.w = (unsigned short)f2b(v.w);
    ((ushort4*)d)[off] = o;
}

// ---------------- dw_w [2048][9] -> tap-major [9][2048] fp32 -------------------
__global__ __launch_bounds__(256) void cvt_dw(
    const float* __restrict__ src, float* __restrict__ dst) {
    int i = blockIdx.x * 256 + threadIdx.x;   // 72 blocks -> 18432
    int t = i >> 11, c = i & 2047;
    dst[t * 2048 + c] = src[c * 9 + t];
}

// ---------------- layernorm: fp32 [8192][512] -> bf16, one wave per row --------
__global__ __launch_bounds__(256) void ln_kernel(
    const float* __restrict__ x, const float* __restrict__ g,
    const float* __restrict__ b, short* __restrict__ y) {
    int row  = blockIdx.x * 4 + (threadIdx.x >> 6);
    int lane = threadIdx.x & 63;
    const float* xr = x + (long)row * 512 + lane * 8;
    float4 v0 = ((const float4*)xr)[0];
    float4 v1 = ((const float4*)xr)[1];
    float e0[8] = {v0.x, v0.y, v0.z, v0.w, v1.x, v1.y, v1.z, v1.w};
    float s = 0.f;
#pragma unroll
    for (int e = 0; e < 8; e++) s += e0[e];
#pragma unroll
    for (int d = 1; d < 64; d <<= 1) s += __shfl_xor(s, d);
    float mu = s * (1.0f / 512.0f);
    float q = 0.f;
#pragma unroll
    for (int e = 0; e < 8; e++) { float t = e0[e] - mu; q += t * t; }
#pragma unroll
    for (int d = 1; d < 64; d <<= 1) q += __shfl_xor(q, d);
    float rs = rsqrtf(q * (1.0f / 512.0f) + 1e-5f);
    const float* gp = g + lane * 8;
    const float* bp = b + lane * 8;
    short8 o;
#pragma unroll
    for (int e = 0; e < 8; e++) o[e] = f2b((e0[e] - mu) * rs * gp[e] + bp[e]);
    *(short8*)(y + (long)row * 512 + lane * 8) = o;
}

// ---------------- GEMM: C[r][o] = sum_c A[r][c]*B[o][c], A,B bf16 --------------
// MT x 128 tile, BK=64, 4 waves. MT=128: waves 2x2, 4x4 frags. MT=64: waves
// 1x4 (each 64x32), 4x2 frags (2x grid for TLP-starved shapes). Rows are 64
// shorts (8 chunks of 16B); LDS slot s of row r holds global chunk s^(r&7):
// b128 reads from 16 consecutive rows span 8 slot-quads x2 lanes = 2-way (free).
template <int MT, typename Epi>
__global__ __launch_bounds__(256, 4) void gemm_bt(
    const short* __restrict__ A, const short* __restrict__ B, int K, Epi epi) {
    constexpr int NJ = (MT == 128) ? 4 : 2;   // n-frags per wave
    __shared__ short As[MT * 64];
    __shared__ short Bs[128 * 64];
    int tid = threadIdx.x;
    int lane = tid & 63, w = tid >> 6;
    int lr = lane & 15, lq = lane >> 4;
    int wm = (MT == 128) ? (w & 1) * 64 : 0;
    int wn = (MT == 128) ? (w >> 1) * 64 : w * 32;
    long r0 = (long)blockIdx.x * MT, o0 = (long)blockIdx.y * 128;
    f32x4 acc[4][NJ];
#pragma unroll
    for (int i = 0; i < 4; i++)
#pragma unroll
        for (int j = 0; j < NJ; j++) acc[i][j] = (f32x4){0.f, 0.f, 0.f, 0.f};
    const short* Ab = A + r0 * K;
    const short* Bb = B + o0 * K;
    // staging: thread -> (srow = tid>>3 in 0..31, slot = tid&7); source chunk
    // XOR-swizzled; each round covers 32 rows; LDS dest = waveBase + lane*16.
    int srow = tid >> 3;
    int sc = ((tid & 7) ^ (srow & 7)) * 8;    // element offset of source chunk
    for (int k0 = 0; k0 < K; k0 += 64) {
#pragma unroll
        for (int m = 0; m < MT / 32; m++)
            gload_lds16(Ab + (long)(srow + m * 32) * K + k0 + sc,
                        As + m * 2048 + w * 512);
#pragma unroll
        for (int m = 0; m < 4; m++)
            gload_lds16(Bb + (long)(srow + m * 32) * K + k0 + sc,
                        Bs + m * 2048 + w * 512);
        __syncthreads();
#pragma unroll
        for (int ks = 0; ks < 2; ks++) {
            short8 af[4], bfr[NJ];
#pragma unroll
            for (int i = 0; i < 4; i++) {
                int row = wm + i * 16 + lr;
                int c = ks * 4 + lq;
                af[i] = *(const short8*)&As[row * 64 + ((c ^ (row & 7)) * 8)];
            }
#pragma unroll
            for (int j = 0; j < NJ; j++) {
                int row = wn + j * 16 + lr;
                int c = ks * 4 + lq;
                bfr[j] = *(const short8*)&Bs[row * 64 + ((c ^ (row & 7)) * 8)];
            }
#pragma unroll
            for (int i = 0; i < 4; i++)
#pragma unroll
                for (int j = 0; j < NJ; j++)
                    acc[i][j] = __builtin_amdgcn_mfma_f32_16x16x32_bf16(
                        af[i], bfr[j], acc[i][j], 0, 0, 0);
        }
        __syncthreads();
    }
    // C/D layout: col = lane&15, row = (lane>>4)*4 + reg  [m89/m91 verified]
#pragma unroll
    for (int i = 0; i < 4; i++)
#pragma unroll
        for (int j = 0; j < NJ; j++)
#pragma unroll
            for (int rg = 0; rg < 4; rg++)
                epi((int)(r0 + wm + i * 16 + lq * 4 + rg),
                    (int)(o0 + wn + j * 16 + lr), acc[i][j][rg]);
}

// epilogues
struct EpiQKV {   // scatter qkv -> q[bh][n][d], k[bh][n][d], vt[bh][d][n]
    short *q, *k, *vt;
    __device__ void operator()(int r, int o, float v) const {
        int b = r >> 10, n = r & 1023;
        int h = o / 192, j = o - h * 192;
        int bh = b * 8 + h;
        short bv = f2b(v);
        if (j < 64)        q[((long)bh * 1024 + n) * 64 + j] = bv;
        else if (j < 128)  k[((long)bh * 1024 + n) * 64 + (j - 64)] = bv;
        else               vt[((long)bh * 64 + (j - 128)) * 1024 + n] = bv;
    }
};
struct EpiProj {  // x1 = acc + proj_b + x   (fp32)
    const float* pb; const float* x; float* x1;
    __device__ void operator()(int r, int o, float v) const {
        long idx = (long)r * 512 + o;
        x1[idx] = v + pb[o] + x[idx];
    }
};
struct EpiBias {  // h1 = bf16(acc + bias)
    const float* bias; short* out; int O;
    __device__ void operator()(int r, int o, float v) const {
        out[(long)r * O + o] = f2b(v + bias[o]);
    }
};
struct EpiFc2 {   // out = acc + fc2_b + x1  (fp32)
    const float* bias; const float* x1; float* out;
    __device__ void operator()(int r, int o, float v) const {
        long idx = (long)r * 512 + o;
        out[idx] = v + bias[o] + x1[idx];
    }
};

// ---------------- fused attention R9 -------------------------------------------
// Block = (bh, 64 q). Wave w owns q rows [w*16, w*16+16) and ALL 1024 keys.
// 16 iters of 64-key shared tiles, double-buffered: __syncthreads drains
// stage(it) (issued one iter earlier), prefetch stage(it+1) issued after the
// barrier flies across compute(it). S^T = K @ Q^T (A=K, B=Q): lane's col = its
// q-row -> in-lane l, P^T write b64; P/K/V all in GEMM-verified XOR-chunk
// layout (stride 64, slot = chunk ^ (row&7)) -> conflict-free b128 reads.
// exp2-folded softmax. LDS 40KB -> 4 blocks/CU; no cross-wave merge.
__global__ __launch_bounds__(256, 4) void attn_kernel(
    const short* __restrict__ Q, const short* __restrict__ K,
    const short* __restrict__ Vt, short* __restrict__ out) {
    __shared__ __align__(16) char smem[40960];
    int bh = blockIdx.x, qb = blockIdx.y;
    int tid = threadIdx.x, w = tid >> 6, lane = tid & 63;
    int lr = lane & 15, lq = lane >> 4;
    short* Pt = (short*)(smem + 32768) + w * 1024;   // 16 q x 64 keys, XOR-chunked

    const short* Qb = Q + ((long)bh * 1024 + qb * 64 + w * 16) * 64;
    const short* Kb = K + (long)bh * 1024 * 64;
    const short* Vb = Vt + (long)bh * 64 * 1024;

    int srow8 = lane >> 3, slot = lane & 7;   // staging: 8 rows x 8 chunks per wave-round

    short8 qf[2];
    qf[0] = *(const short8*)(Qb + lr * 64 + lq * 8);
    qf[1] = *(const short8*)(Qb + lr * 64 + 32 + lq * 8);

    f32x4 oacc[4];
#pragma unroll
    for (int dt = 0; dt < 4; dt++) oacc[dt] = (f32x4){0.f, 0.f, 0.f, 0.f};
    float lsum = 0.f;

    // prologue: stage tile 0 (K -> smem[0..8K), V -> smem[16K..24K))
#pragma unroll
    for (int m = 0; m < 2; m++) {
        int row = m * 32 + w * 8 + srow8;
        gload_lds16(Kb + (long)row * 64 + ((slot ^ (row & 7)) * 8),
                    (short*)smem + (m * 32 + w * 8) * 64);
        gload_lds16(Vb + (long)row * 1024 + ((slot ^ (row & 7)) * 8),
                    (short*)(smem + 16384) + (m * 32 + w * 8) * 64);
    }

    for (int it = 0; it < 16; it++) {
        __syncthreads();   // drains vmcnt -> stage(it) landed
        int cb = (it & 1) * 8192;
        if (it + 1 < 16) {
            int n0 = (it + 1) * 64, nb = ((it + 1) & 1) * 8192;
#pragma unroll
            for (int m = 0; m < 2; m++) {
                int row = m * 32 + w * 8 + srow8;
                gload_lds16(Kb + (long)(n0 + row) * 64 + ((slot ^ (row & 7)) * 8),
                            (short*)(smem + nb) + (m * 32 + w * 8) * 64);
                gload_lds16(Vb + (long)row * 1024 + n0 + ((slot ^ (row & 7)) * 8),
                            (short*)(smem + 16384 + nb) + (m * 32 + w * 8) * 64);
            }
        }
        const short* Kt = (const short*)(smem + cb);
        const short* Vl = (const short*)(smem + 16384 + cb);
        // S^T[64 keys][16 q] = K @ Q^T
        f32x4 sacc[4];
#pragma unroll
        for (int kt = 0; kt < 4; kt++) sacc[kt] = (f32x4){0.f, 0.f, 0.f, 0.f};
#pragma unroll
        for (int ks = 0; ks < 2; ks++)
#pragma unroll
            for (int kt = 0; kt < 4; kt++) {
                int row = kt * 16 + lr;
                short8 ak = *(const short8*)&Kt[row * 64 +
                                                (((ks * 4 + lq) ^ (row & 7)) * 8)];
                sacc[kt] = __builtin_amdgcn_mfma_f32_16x16x32_bf16(
                    ak, qf[ks], sacc[kt], 0, 0, 0);
            }
        // p = 2^(0.1803*s) (softmax-equiv of e^(s/8)); in-lane l; pack -> Pt
#pragma unroll
        for (int kt = 0; kt < 4; kt++) {
            float e0 = exp2f(sacc[kt][0] * 0.18033688f);
            float e1 = exp2f(sacc[kt][1] * 0.18033688f);
            float e2 = exp2f(sacc[kt][2] * 0.18033688f);
            float e3 = exp2f(sacc[kt][3] * 0.18033688f);
            lsum += (e0 + e1) + (e2 + e3);
            uint2 pk;
            pk.x = (__float_as_uint(e1) & 0xffff0000u) | (__float_as_uint(e0) >> 16);
            pk.y = (__float_as_uint(e3) & 0xffff0000u) | (__float_as_uint(e2) >> 16);
            int chunk = kt * 2 + (lq >> 1);
            *(uint2*)&Pt[lr * 64 + ((chunk ^ (lr & 7)) * 8) + (lq & 1) * 4] = pk;
        }
        // O[16 q][64 d] += P @ V
#pragma unroll
        for (int ks = 0; ks < 2; ks++) {
            short8 ap = *(const short8*)&Pt[lr * 64 +
                                            (((ks * 4 + lq) ^ (lr & 7)) * 8)];
#pragma unroll
            for (int dt = 0; dt < 4; dt++) {
                int row = dt * 16 + lr;
                short8 bv = *(const short8*)&Vl[row * 64 +
                                                (((ks * 4 + lq) ^ (row & 7)) * 8)];
                oacc[dt] = __builtin_amdgcn_mfma_f32_16x16x32_bf16(
                    ap, bv, oacc[dt], 0, 0, 0);
            }
        }
    }
    // l: reduce over lq groups (each lane's col is one q-row)
    lsum += __shfl_xor(lsum, 16);
    lsum += __shfl_xor(lsum, 32);
    float inv = 1.0f / lsum;      // valid for q = lr on every lane
    int b = bh >> 3, h = bh & 7;
    int qbase = qb * 64 + w * 16;
#pragma unroll
    for (int rg = 0; rg < 4; rg++) {
        float iv = __shfl(inv, lq * 4 + rg);
        long base = ((long)(b * 1024 + qbase + lq * 4 + rg)) * 512 + h * 64;
#pragma unroll
        for (int dt = 0; dt < 4; dt++)
            out[base + dt * 16 + lr] = f2b(oacc[dt][rg] * iv);
    }
}

// ---------------- depthwise 3x3 conv + bias + exact GeLU (R8 row-tiled) --------
__global__ __launch_bounds__(256, 3) void dwconv_gelu(
    const short* __restrict__ h1, const float* __restrict__ wdT,
    const float* __restrict__ bias, short* __restrict__ h2) {
    int ch = blockIdx.x & 1, xq = (blockIdx.x >> 1) & 3;
    int yy = (blockIdx.x >> 3) & 31, b = blockIdx.x >> 8;
    int c0 = ch * 1024 + threadIdx.x * 4;
    int x0 = xq * 8;
    float w[9][4];
#pragma unroll
    for (int t = 0; t < 9; t++) {
        float4 v = *(const float4*)&wdT[t * 2048 + c0];
        w[t][0] = v.x; w[t][1] = v.y; w[t][2] = v.z; w[t][3] = v.w;
    }
    float4 bv = *(const float4*)&bias[c0];
    float acc[8][4];
#pragma unroll
    for (int xi = 0; xi < 8; xi++) {
        acc[xi][0] = bv.x; acc[xi][1] = bv.y; acc[xi][2] = bv.z; acc[xi][3] = bv.w;
    }
#pragma unroll
    for (int ky = 0; ky < 3; ky++) {
        int ys = yy + ky - 1;
        if (ys < 0 || ys > 31) continue;      // wave-uniform
        const short* rp = h1 + ((long)(b * 1024 + ys * 32) * 2048 + c0);
        float fa[4], fb[4], fc[4];
        if (x0 > 0) {
            s16x4 v = *(const s16x4*)(rp + (long)(x0 - 1) * 2048);
#pragma unroll
            for (int e = 0; e < 4; e++) fa[e] = b2f(v[e]);
        } else {
#pragma unroll
            for (int e = 0; e < 4; e++) fa[e] = 0.f;
        }
        {
            s16x4 v = *(const s16x4*)(rp + (long)x0 * 2048);
#pragma unroll
            for (int e = 0; e < 4; e++) fb[e] = b2f(v[e]);
        }
#pragma unroll
        for (int xi = 0; xi < 8; xi++) {
            int xs = x0 + xi + 1;
            if (xs <= 31) {
                s16x4 v = *(const s16x4*)(rp + (long)xs * 2048);
#pragma unroll
                for (int e = 0; e < 4; e++) fc[e] = b2f(v[e]);
            } else {
#pragma unroll
                for (int e = 0; e < 4; e++) fc[e] = 0.f;
            }
#pragma unroll
            for (int e = 0; e < 4; e++)
                acc[xi][e] += fa[e] * w[ky * 3][e] + fb[e] * w[ky * 3 + 1][e] +
                              fc[e] * w[ky * 3 + 2][e];
#pragma unroll
            for (int e = 0; e < 4; e++) { fa[e] = fb[e]; fb[e] = fc[e]; }
        }
    }
#pragma unroll
    for (int xi = 0; xi < 8; xi++) {
        s16x4 o;
#pragma unroll
        for (int e = 0; e < 4; e++) {
            float a = acc[xi][e];
            o[e] = f2b(0.5f * a * (1.0f + erf_fast(a * 0.70710678118f)));
        }
        *(s16x4*)&h2[(long)(b * 1024 + yy * 32 + x0 + xi) * 2048 + c0] = o;
    }
}

// ---------------- driver --------------------------------------------------------
extern "C" void kernel_launch(void* const* d_in, const int* in_sizes, int n_in,
                              void* d_out, int out_size, void* d_ws, size_t ws_size,
                              hipStream_t stream) {
    const float* x      = (const float*)d_in[0];
    const float* ln1_g  = (const float*)d_in[1];
    const float* ln1_b  = (const float*)d_in[2];
    const float* qkv_w  = (const float*)d_in[3];
    const float* proj_w = (const float*)d_in[4];
    const float* proj_b = (const float*)d_in[5];
    const float* ln2_g  = (const float*)d_in[6];
    const float* ln2_b  = (const float*)d_in[7];
    const float* fc1_w  = (const float*)d_in[8];
    const float* fc1_b  = (const float*)d_in[9];
    const float* dw_w   = (const float*)d_in[10];
    const float* dw_b   = (const float*)d_in[11];
    const float* fc2_w  = (const float*)d_in[12];
    const float* fc2_b  = (const float*)d_in[13];
    float* out = (float*)d_out;

    char* p = (char*)d_ws;
    short* wq   = (short*)p; p += (long)1536 * 512 * 2;
    short* wp   = (short*)p; p += (long)512 * 512 * 2;
    short* w1   = (short*)p; p += (long)2048 * 512 * 2;
    short* w2   = (short*)p; p += (long)512 * 2048 * 2;
    float* wdT  = (float*)p; p += (long)9 * 2048 * 4;
    short* y1   = (short*)p; p += (long)8192 * 512 * 2;
    short* q    = (short*)p; p += (long)64 * 1024 * 64 * 2;
    short* k    = (short*)p; p += (long)64 * 1024 * 64 * 2;
    short* vt   = (short*)p; p += (long)64 * 64 * 1024 * 2;
    short* attn = (short*)p; p += (long)8192 * 512 * 2;
    float* x1   = (float*)p; p += (long)8192 * 512 * 4;
    short* y2   = (short*)p; p += (long)8192 * 512 * 2;
    short* h1   = (short*)p; p += (long)8192 * 2048 * 2;
    short* h2   = (short*)p; p += (long)8192 * 2048 * 2;
    if ((size_t)(p - (char*)d_ws) > ws_size) return;  // ws too small: fail loudly

    cvt_weights<<<3072, 256, 0, stream>>>(qkv_w, proj_w, fc1_w, fc2_w, wq, wp, w1, w2);
    cvt_dw<<<72, 256, 0, stream>>>(dw_w, wdT);
    ln_kernel<<<2048, 256, 0, stream>>>(x, ln1_g, ln1_b, y1);
    gemm_bt<128><<<dim3(64, 12), 256, 0, stream>>>(y1, wq, 512, EpiQKV{q, k, vt});
    attn_kernel<<<dim3(64, 16), 256, 0, stream>>>(q, k, vt, attn);
    gemm_bt<64><<<dim3(128, 4), 256, 0, stream>>>(attn, wp, 512,
                                                  EpiProj{proj_b, x, x1});
    ln_kernel<<<2048, 256, 0, stream>>>(x1, ln2_g, ln2_b, y2);
    gemm_bt<128><<<dim3(64, 16), 256, 0, stream>>>(y2, w1, 512,
                                                   EpiBias{fc1_b, h1, 2048});
    dwconv_gelu<<<2048, 256, 0, stream>>>(h1, wdT, dw_b, h2);
    gemm_bt<64><<<dim3(128, 4), 256, 0, stream>>>(h2, w2, 2048,
                                                  EpiFc2{fc2_b, x1, out});
}